// Round 6
// baseline (8165.137 us; speedup 1.0000x reference)
//
#include <hip/hip_runtime.h>
#include <hip/hip_cooperative_groups.h>
#include <math.h>

namespace cg = cooperative_groups;

// Problem constants
#define NN 4096
#define TT 48
#define HH 64
#define GG 256   // 4*H
#define PP 12
#define CAP 192  // ELL slots per row, 3 x 64 -> whole-wave chunk loads, no guard
#define NH (NN * HH)

// ---------------------------------------------------------------------------
// Setup: zero h buffers (4 x NH), fold biases, pack weights:
//   Wp0[k*256+col] = {gcWh0, liWh0}                 (float2)
//   Wp1[k*256+col] = {gcWi1, liWi1, gcWh1, liWh1}   (float4)
// ---------------------------------------------------------------------------
__launch_bounds__(256)
__global__ void k_prep(const float* gcbi0, const float* gcbh0,
                       const float* libi0, const float* libh0,
                       const float* gcbi1, const float* gcbh1,
                       const float* libi1, const float* libh1,
                       const float* gcWh0, const float* liWh0,
                       const float* gcWi1, const float* liWi1,
                       const float* gcWh1, const float* liWh1,
                       float* bias, float* state, float2* Wp0, float4* Wp1) {
  int idx = blockIdx.x * 256 + threadIdx.x;
  int stride = gridDim.x * 256;
  for (int i = idx; i < 4 * NH; i += stride) state[i] = 0.0f;
  for (int i = idx; i < HH * GG; i += stride) {
    Wp0[i] = make_float2(gcWh0[i], liWh0[i]);
    Wp1[i] = make_float4(gcWi1[i], liWi1[i], gcWh1[i], liWh1[i]);
  }
  if (idx < GG) {
    bias[idx]      = gcbi0[idx] + gcbh0[idx] + libi0[idx] + libh0[idx];
    bias[GG + idx] = gcbi1[idx] + gcbh1[idx] + libi1[idx] + libh1[idx];
  }
}

// ---------------------------------------------------------------------------
// Single adj pass: raw ELL (incl. +I diag) + dinv. Zero-fills ALL CAP slots
// (re-poison semantics: d_ws is 0xAA before every launch; padding must be
// (col=0, val=0) so unguarded chunk loads are safe). cnt padded to x4.
// ---------------------------------------------------------------------------
__launch_bounds__(256)
__global__ void k_build(const float* adj, float* dinv,
                        int* ell_col, float* ell_val, int* ell_cnt) {
  int r = blockIdx.x;
  __shared__ int cnt;
  __shared__ float red[256];
  if (threadIdx.x == 0) cnt = 0;
  __syncthreads();
  const float* row = adj + (size_t)r * NN;
  float s = 0.0f;
  for (int c = threadIdx.x; c < NN; c += 256) {
    float a = row[c];
    if (c == r) a += 1.0f;   // A = adj + I
    s += a;
    if (a != 0.0f) {
      int pos = atomicAdd(&cnt, 1);
      if (pos < CAP) {
        ell_col[(size_t)r * CAP + pos] = c;
        ell_val[(size_t)r * CAP + pos] = a;
      }
    }
  }
  red[threadIdx.x] = s;
  __syncthreads();
  for (int st = 128; st > 0; st >>= 1) {
    if (threadIdx.x < st) red[threadIdx.x] += red[threadIdx.x + st];
    __syncthreads();
  }
  int n = cnt < CAP ? cnt : CAP;
  for (int j = n + (int)threadIdx.x; j < CAP; j += 256) {
    ell_col[(size_t)r * CAP + j] = 0;
    ell_val[(size_t)r * CAP + j] = 0.0f;
  }
  if (threadIdx.x == 0) {
    int npad = (n + 3) & ~3;
    if (npad > CAP) npad = CAP;
    ell_cnt[r] = npad;
    dinv[r] = 1.0f / sqrtf(red[0]);  // rowsum + 1 >= 1
  }
}

__launch_bounds__(256)
__global__ void k_scale(const float* dinv, const int* ell_col, float* ell_val) {
  int idx = blockIdx.x * 256 + threadIdx.x;  // over NN*CAP
  int r = idx / CAP;
  if (r >= NN) return;
  float v = ell_val[idx];
  if (v != 0.0f) ell_val[idx] = v * dinv[r] * dinv[ell_col[idx]];
}

// ---------------------------------------------------------------------------
// Precompute gax[t][r][c] = (A @ x_t)[r][c]. Block = (t, 512-row segment).
// ---------------------------------------------------------------------------
__launch_bounds__(256)
__global__ void k_gax(const float* x, const int* ell_col, const float* ell_val,
                      const int* ell_cnt, float* gax) {
  int t = blockIdx.x >> 3;
  int seg = blockIdx.x & 7;
  __shared__ float xs[NN * 2];
  const float* xt = x + (size_t)t * NN * 2;
  for (int i = threadIdx.x; i < NN * 2; i += 256) xs[i] = xt[i];
  __syncthreads();
  int base = seg * 512 * 2;
  for (int oo = threadIdx.x; oo < 512 * 2; oo += 256) {
    int o = base + oo;
    int r = o >> 1, cmp = o & 1;
    int cnt = ell_cnt[r];
    const int* cp = ell_col + (size_t)r * CAP;
    const float* vp = ell_val + (size_t)r * CAP;
    float acc = 0.0f;
    for (int j = 0; j < cnt; j += 4) {
      acc += vp[j]     * xs[cp[j]     * 2 + cmp];
      acc += vp[j + 1] * xs[cp[j + 1] * 2 + cmp];
      acc += vp[j + 2] * xs[cp[j + 2] * 2 + cmp];
      acc += vp[j + 3] * xs[cp[j + 3] * 2 + cmp];
    }
    gax[(size_t)t * NN * 2 + o] = acc;
  }
}

// readlane broadcast helpers (uniform index -> SGPR, off the LDS pipe)
__device__ __forceinline__ int bcast_i(int v, int lane) {
  return __builtin_amdgcn_readlane(v, lane);
}
__device__ __forceinline__ float bcast_f(float v, int lane) {
  return __int_as_float(__builtin_amdgcn_readlane(__float_as_int(v), lane));
}

// ---------------------------------------------------------------------------
// Persistent cooperative kernel: the entire 48-step double-cell recurrence.
// 512 blocks x 256 threads = 2 blocks/CU co-resident (LDS 16.5KB/block).
// Block owns rows [b*8, b*8+8) for all steps. ELL metadata in registers;
// c0/c1 in registers; h double-buffered in global; 2 grid.sync() per step.
// ---------------------------------------------------------------------------
__launch_bounds__(256, 2)
__global__ void k_loop(const int* __restrict__ ell_col, const float* __restrict__ ell_val,
                       const int* __restrict__ ell_cnt,
                       const float* __restrict__ x, const float* __restrict__ gax,
                       const float2* __restrict__ Wp0, const float4* __restrict__ Wp1,
                       const float* __restrict__ gcWi0, const float* __restrict__ liWi0,
                       const float* __restrict__ bias, float* __restrict__ state) {
  cg::grid_group grid = cg::this_grid();
  const int row0 = blockIdx.x * 8;
  const int tid = threadIdx.x;
  const int wave = tid >> 6, lane = tid & 63;

  __shared__ float sbuf[4128];
  float* tileA = sbuf;           // cell0: g (A@h0)   | cell1: gis (A@h0n)
  float* tileB = sbuf + 512;     // cell0: h0 local   | cell1: h0n local
  float* tileC = sbuf + 1024;    //                   | cell1: ghs (A@h1)
  float* tileD = sbuf + 1536;    //                   | cell1: h1 local
  float* comb  = sbuf + 2048;    // [8][256]
  float* xgp   = sbuf + 4096;    // [8][4]: {x0,x1,gax0,gax1}

  // --- ELL into registers: wave w handles rows w and w+4, 3 chunks each ---
  int   myc[2][3];
  float myv[2][3];
  int   cnts[2];
#pragma unroll
  for (int half = 0; half < 2; half++) {
    int r = row0 + wave + half * 4;
    cnts[half] = ell_cnt[r];
#pragma unroll
    for (int ch = 0; ch < 3; ch++) {
      myc[half][ch] = ell_col[(size_t)r * CAP + ch * 64 + lane];
      myv[half][ch] = ell_val[(size_t)r * CAP + ch * 64 + lane];
    }
  }

  // x-part weights for this thread's column (loop-invariant, 8 regs)
  const int col = tid;
  const float wg0 = gcWi0[col], wg1 = gcWi0[GG + col];
  const float wl0 = liWi0[col], wl1 = liWi0[GG + col];
  const float b0 = bias[col], b1 = bias[GG + col];

  float creg0[2] = {0.0f, 0.0f};
  float creg1[2] = {0.0f, 0.0f};

  float* h0buf[2] = {state, state + NH};
  float* h1buf[2] = {state + 2 * NH, state + 3 * NH};

  for (int t = 0; t < TT; t++) {
    int cur = t & 1;
    const float* h0r = h0buf[cur];
    float* h0w = h0buf[cur ^ 1];

    // ================= cell 0 =================
#pragma unroll
    for (int half = 0; half < 2; half++) {
      int rr = wave + half * 4;
      int cnt = cnts[half];
      float acc = 0.0f;
#pragma unroll
      for (int ch = 0; ch < 3; ch++) {
        int base = ch * 64;
        if (base < cnt) {
          int lim = cnt - base; if (lim > 64) lim = 64;
          int mc = myc[half][ch];
          float mv = myv[half][ch];
          for (int m = 0; m < lim; m += 4) {
            int cA = bcast_i(mc, m),     cB = bcast_i(mc, m + 1);
            int cC = bcast_i(mc, m + 2), cD = bcast_i(mc, m + 3);
            float vA = bcast_f(mv, m),     vB = bcast_f(mv, m + 1);
            float vC = bcast_f(mv, m + 2), vD = bcast_f(mv, m + 3);
            acc += vA * h0r[(size_t)cA * HH + lane];
            acc += vB * h0r[(size_t)cB * HH + lane];
            acc += vC * h0r[(size_t)cC * HH + lane];
            acc += vD * h0r[(size_t)cD * HH + lane];
          }
        }
      }
      tileA[rr * 64 + lane] = acc;
    }
    for (int i = tid; i < 512; i += 256) tileB[i] = h0r[(size_t)row0 * HH + i];
    if (tid < 16) {
      int rr = tid >> 1, cc = tid & 1;
      xgp[rr * 4 + cc]     = x[((size_t)t * NN + row0 + rr) * 2 + cc];
      xgp[rr * 4 + 2 + cc] = gax[((size_t)t * NN + row0 + rr) * 2 + cc];
    }
    __syncthreads();

    // dense: comb = gax@gcWi0 + x@liWi0 + g@gcWh0 + h0@liWh0 + b0
    {
      float acc[8];
#pragma unroll
      for (int r = 0; r < 8; r++) {
        acc[r] = b0 + xgp[r * 4 + 2] * wg0 + xgp[r * 4 + 3] * wg1
                    + xgp[r * 4 + 0] * wl0 + xgp[r * 4 + 1] * wl1;
      }
      for (int k = 0; k < 64; k += 4) {
        float2 w[4];
#pragma unroll
        for (int i = 0; i < 4; i++) w[i] = Wp0[(k + i) * GG + col];
#pragma unroll
        for (int r = 0; r < 8; r++) {
          float4 gv = *reinterpret_cast<const float4*>(&tileA[r * 64 + k]);
          float4 hv = *reinterpret_cast<const float4*>(&tileB[r * 64 + k]);
          acc[r] += gv.x * w[0].x + gv.y * w[1].x + gv.z * w[2].x + gv.w * w[3].x
                  + hv.x * w[0].y + hv.y * w[1].y + hv.z * w[2].y + hv.w * w[3].y;
        }
      }
#pragma unroll
      for (int r = 0; r < 8; r++) comb[r * 256 + col] = acc[r];
    }
    __syncthreads();

#pragma unroll
    for (int p = 0; p < 2; p++) {
      int o = tid + p * 256;
      int rr = o >> 6, hc = o & 63;
      float ig = comb[rr * 256 + hc];
      float fg = comb[rr * 256 + hc + 64];
      float og = comb[rr * 256 + hc + 128];
      float gg = comb[rr * 256 + hc + 192];
      float cprev = creg0[p];
      float si = 1.0f / (1.0f + __expf(-ig));
      float sf = 1.0f / (1.0f + __expf(-fg));
      float so = 1.0f / (1.0f + __expf(-og));
      float cn = sf * cprev + si * tanhf(gg);
      float hn = so * tanhf(cn);
      creg0[p] = cn;
      h0w[(size_t)row0 * HH + o] = hn;
    }
    grid.sync();

    // ================= cell 1 =================
    const float* h1r = h1buf[cur];
    float* h1w = h1buf[cur ^ 1];
    const float* h0n = h0w;

#pragma unroll
    for (int half = 0; half < 2; half++) {
      int rr = wave + half * 4;
      int cnt = cnts[half];
      float a0 = 0.0f, a1 = 0.0f;
#pragma unroll
      for (int ch = 0; ch < 3; ch++) {
        int base = ch * 64;
        if (base < cnt) {
          int lim = cnt - base; if (lim > 64) lim = 64;
          int mc = myc[half][ch];
          float mv = myv[half][ch];
          for (int m = 0; m < lim; m += 2) {
            int cA = bcast_i(mc, m), cB = bcast_i(mc, m + 1);
            float vA = bcast_f(mv, m), vB = bcast_f(mv, m + 1);
            a0 += vA * h0n[(size_t)cA * HH + lane];
            a1 += vA * h1r[(size_t)cA * HH + lane];
            a0 += vB * h0n[(size_t)cB * HH + lane];
            a1 += vB * h1r[(size_t)cB * HH + lane];
          }
        }
      }
      tileA[rr * 64 + lane] = a0;
      tileC[rr * 64 + lane] = a1;
    }
    for (int i = tid; i < 512; i += 256) {
      tileB[i] = h0n[(size_t)row0 * HH + i];
      tileD[i] = h1r[(size_t)row0 * HH + i];
    }
    __syncthreads();

    // dense: comb = gis@gcWi1 + h0n@liWi1 + ghs@gcWh1 + h1@liWh1 + b1
    {
      float acc[8];
#pragma unroll
      for (int r = 0; r < 8; r++) acc[r] = b1;
      for (int k = 0; k < 64; k += 4) {
        float4 w[4];
#pragma unroll
        for (int i = 0; i < 4; i++) w[i] = Wp1[(k + i) * GG + col];
#pragma unroll
        for (int r = 0; r < 8; r++) {
          float4 av = *reinterpret_cast<const float4*>(&tileA[r * 64 + k]);
          float4 bv = *reinterpret_cast<const float4*>(&tileB[r * 64 + k]);
          float4 cv = *reinterpret_cast<const float4*>(&tileC[r * 64 + k]);
          float4 dv = *reinterpret_cast<const float4*>(&tileD[r * 64 + k]);
          acc[r] += av.x * w[0].x + av.y * w[1].x + av.z * w[2].x + av.w * w[3].x
                  + bv.x * w[0].y + bv.y * w[1].y + bv.z * w[2].y + bv.w * w[3].y
                  + cv.x * w[0].z + cv.y * w[1].z + cv.z * w[2].z + cv.w * w[3].z
                  + dv.x * w[0].w + dv.y * w[1].w + dv.z * w[2].w + dv.w * w[3].w;
        }
      }
#pragma unroll
      for (int r = 0; r < 8; r++) comb[r * 256 + col] = acc[r];
    }
    __syncthreads();

#pragma unroll
    for (int p = 0; p < 2; p++) {
      int o = tid + p * 256;
      int rr = o >> 6, hc = o & 63;
      float ig = comb[rr * 256 + hc];
      float fg = comb[rr * 256 + hc + 64];
      float og = comb[rr * 256 + hc + 128];
      float gg = comb[rr * 256 + hc + 192];
      float cprev = creg1[p];
      float si = 1.0f / (1.0f + __expf(-ig));
      float sf = 1.0f / (1.0f + __expf(-fg));
      float so = 1.0f / (1.0f + __expf(-og));
      float cn = sf * cprev + si * tanhf(gg);
      float hn = so * tanhf(cn);
      creg1[p] = cn;
      h1w[(size_t)row0 * HH + o] = hn;
    }
    grid.sync();
  }
}

// ---------------------------------------------------------------------------
// Output projection: out[r,p] = h1[r,:] @ outW[:,p] + outb[p].
// ---------------------------------------------------------------------------
__launch_bounds__(256)
__global__ void k_out(const float* __restrict__ h1, const float* __restrict__ outW,
                      const float* __restrict__ outb, float* __restrict__ out) {
  int idx = blockIdx.x * 256 + threadIdx.x;
  if (idx >= NN * PP) return;
  int r = idx / PP, p = idx - r * PP;
  float acc = outb[p];
  const float* hrow = h1 + (size_t)r * HH;
#pragma unroll 16
  for (int k = 0; k < HH; k++) acc += hrow[k] * outW[k * PP + p];
  out[idx] = acc;
}

extern "C" void kernel_launch(void* const* d_in, const int* in_sizes, int n_in,
                              void* d_out, int out_size, void* d_ws, size_t ws_size,
                              hipStream_t stream) {
  const float* x     = (const float*)d_in[0];
  const float* adj   = (const float*)d_in[1];
  const float* gcWi0 = (const float*)d_in[2];
  const float* gcbi0 = (const float*)d_in[3];
  const float* gcWh0 = (const float*)d_in[4];
  const float* gcbh0 = (const float*)d_in[5];
  const float* liWi0 = (const float*)d_in[6];
  const float* libi0 = (const float*)d_in[7];
  const float* liWh0 = (const float*)d_in[8];
  const float* libh0 = (const float*)d_in[9];
  const float* gcWi1 = (const float*)d_in[10];
  const float* gcbi1 = (const float*)d_in[11];
  const float* gcWh1 = (const float*)d_in[12];
  const float* gcbh1 = (const float*)d_in[13];
  const float* liWi1 = (const float*)d_in[14];
  const float* libi1 = (const float*)d_in[15];
  const float* liWh1 = (const float*)d_in[16];
  const float* libh1 = (const float*)d_in[17];
  const float* outW  = (const float*)d_in[18];
  const float* outb  = (const float*)d_in[19];

  char* ws = (char*)d_ws;
  size_t off = 0;
  auto carve = [&](size_t bytes) {
    void* p = ws + off;
    off += (bytes + 255) & ~(size_t)255;
    return p;
  };
  float*  dinv    = (float*)carve((size_t)NN * 4);
  int*    ell_col = (int*)carve((size_t)NN * CAP * 4);
  float*  ell_val = (float*)carve((size_t)NN * CAP * 4);
  int*    ell_cnt = (int*)carve((size_t)NN * 4);
  float*  bias    = (float*)carve((size_t)2 * GG * 4);
  float*  state   = (float*)carve((size_t)4 * NH * 4);
  float*  gax     = (float*)carve((size_t)TT * NN * 2 * 4);
  float2* Wp0     = (float2*)carve((size_t)HH * GG * 8);
  float4* Wp1     = (float4*)carve((size_t)HH * GG * 16);

  k_prep<<<512, 256, 0, stream>>>(gcbi0, gcbh0, libi0, libh0,
                                  gcbi1, gcbh1, libi1, libh1,
                                  gcWh0, liWh0, gcWi1, liWi1, gcWh1, liWh1,
                                  bias, state, Wp0, Wp1);
  k_build<<<NN, 256, 0, stream>>>(adj, dinv, ell_col, ell_val, ell_cnt);
  k_scale<<<(NN * CAP) / 256, 256, 0, stream>>>(dinv, ell_col, ell_val);
  k_gax<<<TT * 8, 256, 0, stream>>>(x, ell_col, ell_val, ell_cnt, gax);

  {
    void* args[] = {(void*)&ell_col, (void*)&ell_val, (void*)&ell_cnt,
                    (void*)&x, (void*)&gax, (void*)&Wp0, (void*)&Wp1,
                    (void*)&gcWi0, (void*)&liWi0, (void*)&bias, (void*)&state};
    hipLaunchCooperativeKernel((const void*)k_loop, dim3(512), dim3(256),
                               args, 0, stream);
  }

  // final h1 is h1buf[0] = state + 2*NH (t=47: cur=1, writes buf[cur^1]=0)
  k_out<<<(NN * PP + 255) / 256, 256, 0, stream>>>(state + 2 * NH, outW, outb,
                                                   (float*)d_out);
}

// Round 7
// 5178.953 us; speedup vs baseline: 1.5766x; 1.5766x over previous
//
#include <hip/hip_runtime.h>
#include <math.h>

// Problem constants
#define NN 4096
#define TT 48
#define HH 64
#define GG 256   // 4*H
#define PP 12
#define CAP 192  // ELL slots per row, 3 x 64 -> whole-wave chunk loads, no guard
#define NH (NN * HH)

// readlane broadcast helpers (uniform lane index -> SGPR, off the LDS pipe)
__device__ __forceinline__ int bcast_i(int v, int lane) {
  return __builtin_amdgcn_readlane(v, lane);
}
__device__ __forceinline__ float bcast_f(float v, int lane) {
  return __int_as_float(__builtin_amdgcn_readlane(__float_as_int(v), lane));
}
// float4 component by (unroll-constant) index
__device__ __forceinline__ float f4c(const float4& v, int q) {
  switch (q) { case 0: return v.x; case 1: return v.y; case 2: return v.z; default: return v.w; }
}

// ---------------------------------------------------------------------------
// Setup: zero state (4 h + 2 c), fold biases, pack weights for the readlane
// dense scheme. Col mapping: wave wp, lane j owns cols c0=wp*64+j, c1=c0+128.
//   Wpk0[((k*2+mat)*2+wp)*64+j] = float2{W[k][c0], W[k][c1]}, mat:{gcWh0,liWh0}
//   Wpk1[((k*4+mat)*2+wp)*64+j] = same, mat:{gcWi1,liWi1,gcWh1,liWh1}
//   biaspk{0,1}[wp*64+j] = float2{b[c0], b[c1]}
//   xwA[wp*64+j] = {gcWi0[0][c0],gcWi0[1][c0],liWi0[0][c0],liWi0[1][c0]}; xwB: c1
// ---------------------------------------------------------------------------
__launch_bounds__(256)
__global__ void k_prep(const float* gcbi0, const float* gcbh0,
                       const float* libi0, const float* libh0,
                       const float* gcbi1, const float* gcbh1,
                       const float* libi1, const float* libh1,
                       const float* gcWh0, const float* liWh0,
                       const float* gcWi1, const float* liWi1,
                       const float* gcWh1, const float* liWh1,
                       const float* gcWi0, const float* liWi0,
                       float* state, float2* Wpk0, float2* Wpk1,
                       float2* biaspk0, float2* biaspk1,
                       float4* xwA, float4* xwB) {
  int idx = blockIdx.x * 256 + threadIdx.x;
  int stride = gridDim.x * 256;
  for (int i = idx; i < 6 * NH; i += stride) state[i] = 0.0f;
  // Wpk0: i = k*256 + mat*128 + wp*64 + j
  for (int i = idx; i < 64 * 256; i += stride) {
    int k = i >> 8, mat = (i >> 7) & 1, wp = (i >> 6) & 1, j = i & 63;
    const float* W = mat ? liWh0 : gcWh0;
    int c0 = wp * 64 + j;
    Wpk0[i] = make_float2(W[k * GG + c0], W[k * GG + c0 + 128]);
  }
  // Wpk1: i = k*512 + mat*128 + wp*64 + j
  for (int i = idx; i < 64 * 512; i += stride) {
    int k = i >> 9, mat = (i >> 7) & 3, wp = (i >> 6) & 1, j = i & 63;
    const float* W = (mat == 0) ? gcWi1 : (mat == 1) ? liWi1 : (mat == 2) ? gcWh1 : liWh1;
    int c0 = wp * 64 + j;
    Wpk1[i] = make_float2(W[k * GG + c0], W[k * GG + c0 + 128]);
  }
  if (idx < 128) {
    int wp = idx >> 6, j = idx & 63;
    int c0 = wp * 64 + j, c1 = c0 + 128;
    biaspk0[idx] = make_float2(
        gcbi0[c0] + gcbh0[c0] + libi0[c0] + libh0[c0],
        gcbi0[c1] + gcbh0[c1] + libi0[c1] + libh0[c1]);
    biaspk1[idx] = make_float2(
        gcbi1[c0] + gcbh1[c0] + libi1[c0] + libh1[c0],
        gcbi1[c1] + gcbh1[c1] + libi1[c1] + libh1[c1]);
    xwA[idx] = make_float4(gcWi0[c0], gcWi0[GG + c0], liWi0[c0], liWi0[GG + c0]);
    xwB[idx] = make_float4(gcWi0[c1], gcWi0[GG + c1], liWi0[c1], liWi0[GG + c1]);
  }
}

// ---------------------------------------------------------------------------
// Single adj pass: raw ELL (incl. +I diag) + dinv. Zero-fills ALL CAP slots
// (re-poison semantics: padding must be (col=0, val=0)). cnt padded to x4.
// ---------------------------------------------------------------------------
__launch_bounds__(256)
__global__ void k_build(const float* adj, float* dinv,
                        int* ell_col, float* ell_val, int* ell_cnt) {
  int r = blockIdx.x;
  __shared__ int cnt;
  __shared__ float red[256];
  if (threadIdx.x == 0) cnt = 0;
  __syncthreads();
  const float* row = adj + (size_t)r * NN;
  float s = 0.0f;
  for (int c = threadIdx.x; c < NN; c += 256) {
    float a = row[c];
    if (c == r) a += 1.0f;   // A = adj + I
    s += a;
    if (a != 0.0f) {
      int pos = atomicAdd(&cnt, 1);
      if (pos < CAP) {
        ell_col[(size_t)r * CAP + pos] = c;
        ell_val[(size_t)r * CAP + pos] = a;
      }
    }
  }
  red[threadIdx.x] = s;
  __syncthreads();
  for (int st = 128; st > 0; st >>= 1) {
    if (threadIdx.x < st) red[threadIdx.x] += red[threadIdx.x + st];
    __syncthreads();
  }
  int n = cnt < CAP ? cnt : CAP;
  for (int j = n + (int)threadIdx.x; j < CAP; j += 256) {
    ell_col[(size_t)r * CAP + j] = 0;
    ell_val[(size_t)r * CAP + j] = 0.0f;
  }
  if (threadIdx.x == 0) {
    int npad = (n + 3) & ~3;
    if (npad > CAP) npad = CAP;
    ell_cnt[r] = npad;
    dinv[r] = 1.0f / sqrtf(red[0]);  // rowsum + 1 >= 1
  }
}

__launch_bounds__(256)
__global__ void k_scale(const float* dinv, const int* ell_col, float* ell_val) {
  int idx = blockIdx.x * 256 + threadIdx.x;  // over NN*CAP
  int r = idx / CAP;
  if (r >= NN) return;
  float v = ell_val[idx];
  if (v != 0.0f) ell_val[idx] = v * dinv[r] * dinv[ell_col[idx]];
}

// ---------------------------------------------------------------------------
// Precompute gax[t][r][c] = (A @ x_t)[r][c]. Block = (t, 512-row segment).
// ---------------------------------------------------------------------------
__launch_bounds__(256)
__global__ void k_gax(const float* x, const int* ell_col, const float* ell_val,
                      const int* ell_cnt, float* gax) {
  int t = blockIdx.x >> 3;
  int seg = blockIdx.x & 7;
  __shared__ float xs[NN * 2];
  const float* xt = x + (size_t)t * NN * 2;
  for (int i = threadIdx.x; i < NN * 2; i += 256) xs[i] = xt[i];
  __syncthreads();
  int base = seg * 512 * 2;
  for (int oo = threadIdx.x; oo < 512 * 2; oo += 256) {
    int o = base + oo;
    int r = o >> 1, cmp = o & 1;
    int cnt = ell_cnt[r];
    const int* cp = ell_col + (size_t)r * CAP;
    const float* vp = ell_val + (size_t)r * CAP;
    float acc = 0.0f;
    for (int j = 0; j < cnt; j += 4) {
      acc += vp[j]     * xs[cp[j]     * 2 + cmp];
      acc += vp[j + 1] * xs[cp[j + 1] * 2 + cmp];
      acc += vp[j + 2] * xs[cp[j + 2] * 2 + cmp];
      acc += vp[j + 3] * xs[cp[j + 3] * 2 + cmp];
    }
    gax[(size_t)t * NN * 2 + o] = acc;
  }
}

// ---------------------------------------------------------------------------
// Cell 0. Block = 8 rows, 128 threads (2 waves). Wave wp gathers rows
// [row0+4wp, row0+4wp+4), stages acts in LDS [r(8)][mat(2)][k(64)]
// (lane-strided, conflict-free), then the dense phase reads the acts ONCE
// per wave as 4 ds_read_b128 of DISTINCT addresses into registers and
// broadcasts each scalar via v_readlane (VALU pipe) — this replaces the
// LDS-broadcast reads that bound R2..R5 cells at ~25us.
// Lane j of wave wp owns cols {wp*64+j, wp*64+j+128}.
// ---------------------------------------------------------------------------
__launch_bounds__(128)
__global__ void k_cell0(const int* __restrict__ ell_col, const float* __restrict__ ell_val,
                        const int* __restrict__ ell_cnt,
                        const float* __restrict__ h0r, float* __restrict__ h0w,
                        float* __restrict__ c0,
                        const float* __restrict__ xt, const float* __restrict__ gaxt,
                        const float2* __restrict__ Wpk0,
                        const float2* __restrict__ biaspk0,
                        const float4* __restrict__ xwA, const float4* __restrict__ xwB) {
  const int row0 = blockIdx.x * 8;
  const int tid = threadIdx.x;
  const int wp = tid >> 6, lane = tid & 63;
  __shared__ float actS[8 * 2 * 64];
  __shared__ float xgS[8 * 4];
  __shared__ float combS[8 * 256];

  // ELL for my 4 rows
  int myc[4][3]; float myv[4][3]; int cnts[4];
#pragma unroll
  for (int rr = 0; rr < 4; rr++) {
    int r = row0 + wp * 4 + rr;
    cnts[rr] = ell_cnt[r];
#pragma unroll
    for (int ch = 0; ch < 3; ch++) {
      myc[rr][ch] = ell_col[(size_t)r * CAP + ch * 64 + lane];
      myv[rr][ch] = ell_val[(size_t)r * CAP + ch * 64 + lane];
    }
  }
  // gather A@h0 for my 4 rows + stage local h0 rows
#pragma unroll
  for (int rr = 0; rr < 4; rr++) {
    int rloc = wp * 4 + rr;
    int cnt = cnts[rr];
    float acc = 0.0f;
#pragma unroll
    for (int ch = 0; ch < 3; ch++) {
      int base = ch * 64;
      if (base < cnt) {
        int lim = cnt - base; if (lim > 64) lim = 64;  // multiple of 4
        int mc = myc[rr][ch]; float mv = myv[rr][ch];
        for (int m = 0; m < lim; m += 4) {
          int cA = bcast_i(mc, m),     cB = bcast_i(mc, m + 1);
          int cC = bcast_i(mc, m + 2), cD = bcast_i(mc, m + 3);
          float vA = bcast_f(mv, m),     vB = bcast_f(mv, m + 1);
          float vC = bcast_f(mv, m + 2), vD = bcast_f(mv, m + 3);
          acc += vA * h0r[(size_t)cA * HH + lane];
          acc += vB * h0r[(size_t)cB * HH + lane];
          acc += vC * h0r[(size_t)cC * HH + lane];
          acc += vD * h0r[(size_t)cD * HH + lane];
        }
      }
    }
    actS[(rloc * 2 + 0) * 64 + lane] = acc;
    actS[(rloc * 2 + 1) * 64 + lane] = h0r[(size_t)(row0 + rloc) * HH + lane];
  }
  if (lane < 16) {  // per-row x/gax scalars: rloc = wp*4 + (lane>>2), comp = lane&3
    int rloc = wp * 4 + (lane >> 2), comp = lane & 3;
    float v = (comp < 2) ? xt[(size_t)(row0 + rloc) * 2 + comp]
                         : gaxt[(size_t)(row0 + rloc) * 2 + (comp - 2)];
    xgS[rloc * 4 + comp] = v;
  }
  __syncthreads();

  // acts -> registers: 4 distinct-address b128 reads (full LDS pipe width)
  float4 av[4];
#pragma unroll
  for (int c = 0; c < 4; c++)
    av[c] = *reinterpret_cast<const float4*>(&actS[c * 256 + lane * 4]);

  // dense: acc[r][cc] = b + x-part + sum_k act*W
  float2 b = biaspk0[wp * 64 + lane];
  float4 wA = xwA[wp * 64 + lane];
  float4 wB = xwB[wp * 64 + lane];
  float acc[8][2];
#pragma unroll
  for (int r = 0; r < 8; r++) {
    float x0 = xgS[r * 4 + 0], x1 = xgS[r * 4 + 1];
    float g0 = xgS[r * 4 + 2], g1 = xgS[r * 4 + 3];
    acc[r][0] = b.x + g0 * wA.x + g1 * wA.y + x0 * wA.z + x1 * wA.w;
    acc[r][1] = b.y + g0 * wB.x + g1 * wB.y + x0 * wB.z + x1 * wB.w;
  }
  for (int k4 = 0; k4 < 64; k4 += 4) {
    int ls = k4 >> 2;  // uniform lane-select base (k/4)
#pragma unroll
    for (int q = 0; q < 4; q++) {
      int k = k4 + q;
      float2 w0 = Wpk0[((k * 2 + 0) * 2 + wp) * 64 + lane];
      float2 w1 = Wpk0[((k * 2 + 1) * 2 + wp) * 64 + lane];
#pragma unroll
      for (int r = 0; r < 8; r++) {
        // act(r,mat,k): R=r*2+mat; chunk=R>>2; lane=(R&3)*16+k/4; comp=k%4
        float a0 = bcast_f(f4c(av[(r * 2 + 0) >> 2], q), ((r * 2 + 0) & 3) * 16 + ls);
        float a1 = bcast_f(f4c(av[(r * 2 + 1) >> 2], q), ((r * 2 + 1) & 3) * 16 + ls);
        acc[r][0] += a0 * w0.x + a1 * w1.x;
        acc[r][1] += a0 * w0.y + a1 * w1.y;
      }
    }
  }
#pragma unroll
  for (int r = 0; r < 8; r++) {
    combS[r * 256 + wp * 64 + lane] = acc[r][0];
    combS[r * 256 + wp * 64 + lane + 128] = acc[r][1];
  }
  __syncthreads();

  // gates: thread owns (rgrp*4+rr, hc)
  int hc = tid & 63, rg = tid >> 6;
#pragma unroll
  for (int rr = 0; rr < 4; rr++) {
    int r = rg * 4 + rr;
    float ig = combS[r * 256 + hc];
    float fg = combS[r * 256 + hc + 64];
    float og = combS[r * 256 + hc + 128];
    float gg = combS[r * 256 + hc + 192];
    size_t gi = (size_t)(row0 + r) * HH + hc;
    float cprev = c0[gi];
    float si = 1.0f / (1.0f + __expf(-ig));
    float sf = 1.0f / (1.0f + __expf(-fg));
    float so = 1.0f / (1.0f + __expf(-og));
    float cn = sf * cprev + si * tanhf(gg);
    float hn = so * tanhf(cn);
    c0[gi] = cn;
    h0w[gi] = hn;
  }
}

// ---------------------------------------------------------------------------
// Cell 1: same structure, 4 act matrices {A@h0n, h0n, A@h1, h1}.
// ---------------------------------------------------------------------------
__launch_bounds__(128)
__global__ void k_cell1(const int* __restrict__ ell_col, const float* __restrict__ ell_val,
                        const int* __restrict__ ell_cnt,
                        const float* __restrict__ h0n,
                        const float* __restrict__ h1r, float* __restrict__ h1w,
                        float* __restrict__ c1,
                        const float2* __restrict__ Wpk1,
                        const float2* __restrict__ biaspk1) {
  const int row0 = blockIdx.x * 8;
  const int tid = threadIdx.x;
  const int wp = tid >> 6, lane = tid & 63;
  __shared__ float actS[8 * 4 * 64];
  __shared__ float combS[8 * 256];

  int myc[4][3]; float myv[4][3]; int cnts[4];
#pragma unroll
  for (int rr = 0; rr < 4; rr++) {
    int r = row0 + wp * 4 + rr;
    cnts[rr] = ell_cnt[r];
#pragma unroll
    for (int ch = 0; ch < 3; ch++) {
      myc[rr][ch] = ell_col[(size_t)r * CAP + ch * 64 + lane];
      myv[rr][ch] = ell_val[(size_t)r * CAP + ch * 64 + lane];
    }
  }
#pragma unroll
  for (int rr = 0; rr < 4; rr++) {
    int rloc = wp * 4 + rr;
    int cnt = cnts[rr];
    float a0 = 0.0f, a1 = 0.0f;
#pragma unroll
    for (int ch = 0; ch < 3; ch++) {
      int base = ch * 64;
      if (base < cnt) {
        int lim = cnt - base; if (lim > 64) lim = 64;
        int mc = myc[rr][ch]; float mv = myv[rr][ch];
        for (int m = 0; m < lim; m += 2) {
          int cA = bcast_i(mc, m), cB = bcast_i(mc, m + 1);
          float vA = bcast_f(mv, m), vB = bcast_f(mv, m + 1);
          a0 += vA * h0n[(size_t)cA * HH + lane];
          a1 += vA * h1r[(size_t)cA * HH + lane];
          a0 += vB * h0n[(size_t)cB * HH + lane];
          a1 += vB * h1r[(size_t)cB * HH + lane];
        }
      }
    }
    actS[(rloc * 4 + 0) * 64 + lane] = a0;
    actS[(rloc * 4 + 1) * 64 + lane] = h0n[(size_t)(row0 + rloc) * HH + lane];
    actS[(rloc * 4 + 2) * 64 + lane] = a1;
    actS[(rloc * 4 + 3) * 64 + lane] = h1r[(size_t)(row0 + rloc) * HH + lane];
  }
  __syncthreads();

  // acts -> registers: 8 distinct-address b128 reads; chunk r = row r's 4 mats
  float4 av[8];
#pragma unroll
  for (int c = 0; c < 8; c++)
    av[c] = *reinterpret_cast<const float4*>(&actS[c * 256 + lane * 4]);

  float2 b = biaspk1[wp * 64 + lane];
  float acc[8][2];
#pragma unroll
  for (int r = 0; r < 8; r++) { acc[r][0] = b.x; acc[r][1] = b.y; }

  for (int k4 = 0; k4 < 64; k4 += 4) {
    int ls = k4 >> 2;
#pragma unroll
    for (int q = 0; q < 4; q++) {
      int k = k4 + q;
      float2 w0 = Wpk1[((k * 4 + 0) * 2 + wp) * 64 + lane];
      float2 w1 = Wpk1[((k * 4 + 1) * 2 + wp) * 64 + lane];
      float2 w2 = Wpk1[((k * 4 + 2) * 2 + wp) * 64 + lane];
      float2 w3 = Wpk1[((k * 4 + 3) * 2 + wp) * 64 + lane];
#pragma unroll
      for (int r = 0; r < 8; r++) {
        // act(r,mat,k): chunk = r; lane = mat*16 + k/4; comp = k%4
        float a0 = bcast_f(f4c(av[r], q), 0 * 16 + ls);
        float a1 = bcast_f(f4c(av[r], q), 1 * 16 + ls);
        float a2 = bcast_f(f4c(av[r], q), 2 * 16 + ls);
        float a3 = bcast_f(f4c(av[r], q), 3 * 16 + ls);
        acc[r][0] += a0 * w0.x + a1 * w1.x + a2 * w2.x + a3 * w3.x;
        acc[r][1] += a0 * w0.y + a1 * w1.y + a2 * w2.y + a3 * w3.y;
      }
    }
  }
#pragma unroll
  for (int r = 0; r < 8; r++) {
    combS[r * 256 + wp * 64 + lane] = acc[r][0];
    combS[r * 256 + wp * 64 + lane + 128] = acc[r][1];
  }
  __syncthreads();

  int hc = tid & 63, rg = tid >> 6;
#pragma unroll
  for (int rr = 0; rr < 4; rr++) {
    int r = rg * 4 + rr;
    float ig = combS[r * 256 + hc];
    float fg = combS[r * 256 + hc + 64];
    float og = combS[r * 256 + hc + 128];
    float gg = combS[r * 256 + hc + 192];
    size_t gi = (size_t)(row0 + r) * HH + hc;
    float cprev = c1[gi];
    float si = 1.0f / (1.0f + __expf(-ig));
    float sf = 1.0f / (1.0f + __expf(-fg));
    float so = 1.0f / (1.0f + __expf(-og));
    float cn = sf * cprev + si * tanhf(gg);
    float hn = so * tanhf(cn);
    c1[gi] = cn;
    h1w[gi] = hn;
  }
}

// ---------------------------------------------------------------------------
// Output projection: out[r,p] = h1[r,:] @ outW[:,p] + outb[p].
// ---------------------------------------------------------------------------
__launch_bounds__(256)
__global__ void k_out(const float* __restrict__ h1, const float* __restrict__ outW,
                      const float* __restrict__ outb, float* __restrict__ out) {
  int idx = blockIdx.x * 256 + threadIdx.x;
  if (idx >= NN * PP) return;
  int r = idx / PP, p = idx - r * PP;
  float acc = outb[p];
  const float* hrow = h1 + (size_t)r * HH;
#pragma unroll 16
  for (int k = 0; k < HH; k++) acc += hrow[k] * outW[k * PP + p];
  out[idx] = acc;
}

extern "C" void kernel_launch(void* const* d_in, const int* in_sizes, int n_in,
                              void* d_out, int out_size, void* d_ws, size_t ws_size,
                              hipStream_t stream) {
  const float* x     = (const float*)d_in[0];
  const float* adj   = (const float*)d_in[1];
  const float* gcWi0 = (const float*)d_in[2];
  const float* gcbi0 = (const float*)d_in[3];
  const float* gcWh0 = (const float*)d_in[4];
  const float* gcbh0 = (const float*)d_in[5];
  const float* liWi0 = (const float*)d_in[6];
  const float* libi0 = (const float*)d_in[7];
  const float* liWh0 = (const float*)d_in[8];
  const float* libh0 = (const float*)d_in[9];
  const float* gcWi1 = (const float*)d_in[10];
  const float* gcbi1 = (const float*)d_in[11];
  const float* gcWh1 = (const float*)d_in[12];
  const float* gcbh1 = (const float*)d_in[13];
  const float* liWi1 = (const float*)d_in[14];
  const float* libi1 = (const float*)d_in[15];
  const float* liWh1 = (const float*)d_in[16];
  const float* libh1 = (const float*)d_in[17];
  const float* outW  = (const float*)d_in[18];
  const float* outb  = (const float*)d_in[19];

  char* ws = (char*)d_ws;
  size_t off = 0;
  auto carve = [&](size_t bytes) {
    void* p = ws + off;
    off += (bytes + 255) & ~(size_t)255;
    return p;
  };
  float*  dinv    = (float*)carve((size_t)NN * 4);
  int*    ell_col = (int*)carve((size_t)NN * CAP * 4);
  float*  ell_val = (float*)carve((size_t)NN * CAP * 4);
  int*    ell_cnt = (int*)carve((size_t)NN * 4);
  float*  state   = (float*)carve((size_t)6 * NH * 4);
  float*  gax     = (float*)carve((size_t)TT * NN * 2 * 4);
  float2* Wpk0    = (float2*)carve((size_t)64 * 256 * 8);
  float2* Wpk1    = (float2*)carve((size_t)64 * 512 * 8);
  float2* biaspk0 = (float2*)carve((size_t)128 * 8);
  float2* biaspk1 = (float2*)carve((size_t)128 * 8);
  float4* xwA     = (float4*)carve((size_t)128 * 16);
  float4* xwB     = (float4*)carve((size_t)128 * 16);

  float* h0buf[2] = {state, state + NH};
  float* h1buf[2] = {state + 2 * NH, state + 3 * NH};
  float* c0 = state + 4 * NH;
  float* c1 = state + 5 * NH;

  k_prep<<<512, 256, 0, stream>>>(gcbi0, gcbh0, libi0, libh0,
                                  gcbi1, gcbh1, libi1, libh1,
                                  gcWh0, liWh0, gcWi1, liWi1, gcWh1, liWh1,
                                  gcWi0, liWi0,
                                  state, Wpk0, Wpk1, biaspk0, biaspk1, xwA, xwB);
  k_build<<<NN, 256, 0, stream>>>(adj, dinv, ell_col, ell_val, ell_cnt);
  k_scale<<<(NN * CAP) / 256, 256, 0, stream>>>(dinv, ell_col, ell_val);
  k_gax<<<TT * 8, 256, 0, stream>>>(x, ell_col, ell_val, ell_cnt, gax);

  for (int t = 0; t < TT; t++) {
    int cur = t & 1;
    k_cell0<<<NN / 8, 128, 0, stream>>>(
        ell_col, ell_val, ell_cnt,
        h0buf[cur], h0buf[cur ^ 1], c0,
        x + (size_t)t * NN * 2, gax + (size_t)t * NN * 2,
        Wpk0, biaspk0, xwA, xwB);
    k_cell1<<<NN / 8, 128, 0, stream>>>(
        ell_col, ell_val, ell_cnt,
        h0buf[cur ^ 1],
        h1buf[cur], h1buf[cur ^ 1], c1,
        Wpk1, biaspk1);
  }

  // final h1 is h1buf[0] (t=47: cur=1, writes buf[0])
  k_out<<<(NN * PP + 255) / 256, 256, 0, stream>>>(state + 2 * NH, outW, outb,
                                                   (float*)d_out);
}

// Round 8
// 3182.782 us; speedup vs baseline: 2.5654x; 1.6272x over previous
//
#include <hip/hip_runtime.h>
#include <math.h>

// Problem constants
#define NN 4096
#define TT 48
#define HH 64
#define GG 256   // 4*H
#define PP 12
#define CAP 192  // ELL slots per row, 3 x 64 -> whole-wave chunk loads, no guard
#define NH (NN * HH)

// readlane broadcast: uniform lane index -> SGPR broadcast, off the LDS pipe
__device__ __forceinline__ float bcast_f(float v, int lane) {
  return __int_as_float(__builtin_amdgcn_readlane(__float_as_int(v), lane));
}
__device__ __forceinline__ int bcast_i(int v, int lane) {
  return __builtin_amdgcn_readlane(v, lane);
}

// ---------------------------------------------------------------------------
// Setup. Col mapping for cells: wave colhalf ch, lane j owns cols
//   c0 = ch*128 + j, c1 = ch*128 + 64 + j.
// Packs:
//   Wpk0[((k*2+mat)*2+ch)*64+j] = {W[k][c0], W[k][c1]}, mat:{gcWh0,liWh0}
//   Wpk1[((k*4+mat)*2+ch)*64+j] = same, mat:{gcWi1,liWi1,gcWh1,liWh1}
//   biaspk{0,1}[ch*64+j] = {b[c0], b[c1]}   (4-way folded biases)
//   xwA[ch*64+j] = {gcWi0[0][c0],gcWi0[1][c0],liWi0[0][c0],liWi0[1][c0]}; xwB: c1
// ---------------------------------------------------------------------------
__launch_bounds__(256)
__global__ void k_prep(const float* gcbi0, const float* gcbh0,
                       const float* libi0, const float* libh0,
                       const float* gcbi1, const float* gcbh1,
                       const float* libi1, const float* libh1,
                       const float* gcWh0, const float* liWh0,
                       const float* gcWi1, const float* liWi1,
                       const float* gcWh1, const float* liWh1,
                       const float* gcWi0, const float* liWi0,
                       float* state, float2* Wpk0, float2* Wpk1,
                       float2* biaspk0, float2* biaspk1,
                       float4* xwA, float4* xwB) {
  int idx = blockIdx.x * 256 + threadIdx.x;
  int stride = gridDim.x * 256;
  for (int i = idx; i < 6 * NH; i += stride) state[i] = 0.0f;
  // Wpk0: i = ((k*2+mat)*2+ch)*64 + j
  for (int i = idx; i < 64 * 256; i += stride) {
    int j = i & 63, ch = (i >> 6) & 1, mat = (i >> 7) & 1, k = i >> 8;
    const float* W = mat ? liWh0 : gcWh0;
    int c0 = ch * 128 + j;
    Wpk0[i] = make_float2(W[k * GG + c0], W[k * GG + c0 + 64]);
  }
  // Wpk1: i = ((k*4+mat)*2+ch)*64 + j
  for (int i = idx; i < 64 * 512; i += stride) {
    int j = i & 63, ch = (i >> 6) & 1, mat = (i >> 7) & 3, k = i >> 9;
    const float* W = (mat == 0) ? gcWi1 : (mat == 1) ? liWi1 : (mat == 2) ? gcWh1 : liWh1;
    int c0 = ch * 128 + j;
    Wpk1[i] = make_float2(W[k * GG + c0], W[k * GG + c0 + 64]);
  }
  if (idx < 128) {
    int ch = idx >> 6, j = idx & 63;
    int c0 = ch * 128 + j, c1 = c0 + 64;
    biaspk0[idx] = make_float2(
        gcbi0[c0] + gcbh0[c0] + libi0[c0] + libh0[c0],
        gcbi0[c1] + gcbh0[c1] + libi0[c1] + libh0[c1]);
    biaspk1[idx] = make_float2(
        gcbi1[c0] + gcbh1[c0] + libi1[c0] + libh1[c0],
        gcbi1[c1] + gcbh1[c1] + libi1[c1] + libh1[c1]);
    xwA[idx] = make_float4(gcWi0[c0], gcWi0[GG + c0], liWi0[c0], liWi0[GG + c0]);
    xwB[idx] = make_float4(gcWi0[c1], gcWi0[GG + c1], liWi0[c1], liWi0[GG + c1]);
  }
}

// ---------------------------------------------------------------------------
// Single adj pass: raw ELL (incl. +I diag) + dinv. Zero-fills ALL CAP slots
// (re-poison semantics: padding must be (col=0, val=0)). cnt padded to x4.
// ---------------------------------------------------------------------------
__launch_bounds__(256)
__global__ void k_build(const float* adj, float* dinv,
                        int* ell_col, float* ell_val, int* ell_cnt) {
  int r = blockIdx.x;
  __shared__ int cnt;
  __shared__ float red[256];
  if (threadIdx.x == 0) cnt = 0;
  __syncthreads();
  const float* row = adj + (size_t)r * NN;
  float s = 0.0f;
  for (int c = threadIdx.x; c < NN; c += 256) {
    float a = row[c];
    if (c == r) a += 1.0f;   // A = adj + I
    s += a;
    if (a != 0.0f) {
      int pos = atomicAdd(&cnt, 1);
      if (pos < CAP) {
        ell_col[(size_t)r * CAP + pos] = c;
        ell_val[(size_t)r * CAP + pos] = a;
      }
    }
  }
  red[threadIdx.x] = s;
  __syncthreads();
  for (int st = 128; st > 0; st >>= 1) {
    if (threadIdx.x < st) red[threadIdx.x] += red[threadIdx.x + st];
    __syncthreads();
  }
  int n = cnt < CAP ? cnt : CAP;
  for (int j = n + (int)threadIdx.x; j < CAP; j += 256) {
    ell_col[(size_t)r * CAP + j] = 0;
    ell_val[(size_t)r * CAP + j] = 0.0f;
  }
  if (threadIdx.x == 0) {
    int npad = (n + 3) & ~3;
    if (npad > CAP) npad = CAP;
    ell_cnt[r] = npad;
    dinv[r] = 1.0f / sqrtf(red[0]);  // rowsum + 1 >= 1
  }
}

__launch_bounds__(256)
__global__ void k_scale(const float* dinv, const int* ell_col, float* ell_val) {
  int idx = blockIdx.x * 256 + threadIdx.x;  // over NN*CAP
  int r = idx / CAP;
  if (r >= NN) return;
  float v = ell_val[idx];
  if (v != 0.0f) ell_val[idx] = v * dinv[r] * dinv[ell_col[idx]];
}

// ---------------------------------------------------------------------------
// Precompute gax[t][r][c] = (A @ x_t)[r][c]. Block = (t, 512-row segment).
// ---------------------------------------------------------------------------
__launch_bounds__(256)
__global__ void k_gax(const float* x, const int* ell_col, const float* ell_val,
                      const int* ell_cnt, float* gax) {
  int t = blockIdx.x >> 3;
  int seg = blockIdx.x & 7;
  __shared__ float xs[NN * 2];
  const float* xt = x + (size_t)t * NN * 2;
  for (int i = threadIdx.x; i < NN * 2; i += 256) xs[i] = xt[i];
  __syncthreads();
  int base = seg * 512 * 2;
  for (int oo = threadIdx.x; oo < 512 * 2; oo += 256) {
    int o = base + oo;
    int r = o >> 1, cmp = o & 1;
    int cnt = ell_cnt[r];
    const int* cp = ell_col + (size_t)r * CAP;
    const float* vp = ell_val + (size_t)r * CAP;
    float acc = 0.0f;
    for (int j = 0; j < cnt; j += 4) {
      acc += vp[j]     * xs[cp[j]     * 2 + cmp];
      acc += vp[j + 1] * xs[cp[j + 1] * 2 + cmp];
      acc += vp[j + 2] * xs[cp[j + 2] * 2 + cmp];
      acc += vp[j + 3] * xs[cp[j + 3] * 2 + cmp];
    }
    gax[(size_t)t * NN * 2 + o] = acc;
  }
}

// ---------------------------------------------------------------------------
// Cell 0. Block = 8 rows, 256 threads (4 waves -> 8 waves/CU at 2 blocks/CU).
// Gather (R5 mechanism): wave w computes A@h0 for rows w, w+4 via register
// ELL + readlane; acts staged to LDS strided (conflict-free). Dense: wave
// (rowgrp=w&1, ch=w>>1) covers 4 rows x 128 cols; acts loaded ONCE into
// registers via distinct-address ds_read_b32 (lane=k), then delivered per-k
// via v_readlane (VALU pipe) — avoids both the R5 LDS-broadcast pipe
// saturation (~20us/CU) and the R7 occupancy collapse (128-thr blocks).
// ---------------------------------------------------------------------------
__launch_bounds__(256, 2)
__global__ void k_cell0(const int* __restrict__ ell_col, const float* __restrict__ ell_val,
                        const int* __restrict__ ell_cnt,
                        const float* __restrict__ h0r, float* __restrict__ h0w,
                        float* __restrict__ c0,
                        const float* __restrict__ xt, const float* __restrict__ gaxt,
                        const float2* __restrict__ Wpk0,
                        const float2* __restrict__ biaspk0,
                        const float4* __restrict__ xwA, const float4* __restrict__ xwB) {
  const int row0 = blockIdx.x * 8;
  const int tid = threadIdx.x;
  const int wave = tid >> 6, lane = tid & 63;
  const int rowgrp = wave & 1, ch = wave >> 1;
  __shared__ float actS[8 * 2 * 64];   // [row][mat(2)][k]
  __shared__ float combS[8 * 256];
  __shared__ float xgS[8 * 4];         // [row][{x0,x1,gax0,gax1}]

  // ELL regs for gather rows (wave, wave+4)
  int myc[2][3]; float myv[2][3]; int cnts[2];
#pragma unroll
  for (int half = 0; half < 2; half++) {
    int r = row0 + wave + half * 4;
    cnts[half] = ell_cnt[r];
#pragma unroll
    for (int chk = 0; chk < 3; chk++) {
      myc[half][chk] = ell_col[(size_t)r * CAP + chk * 64 + lane];
      myv[half][chk] = ell_val[(size_t)r * CAP + chk * 64 + lane];
    }
  }
  // gather A@h0 rows (wave, wave+4)
#pragma unroll
  for (int half = 0; half < 2; half++) {
    int rr = wave + half * 4;
    int cnt = cnts[half];
    float acc = 0.0f;
#pragma unroll
    for (int chk = 0; chk < 3; chk++) {
      int base = chk * 64;
      if (base < cnt) {
        int lim = cnt - base; if (lim > 64) lim = 64;  // multiple of 4
        int mc = myc[half][chk]; float mv = myv[half][chk];
        for (int m = 0; m < lim; m += 4) {
          int cA = bcast_i(mc, m),     cB = bcast_i(mc, m + 1);
          int cC = bcast_i(mc, m + 2), cD = bcast_i(mc, m + 3);
          float vA = bcast_f(mv, m),     vB = bcast_f(mv, m + 1);
          float vC = bcast_f(mv, m + 2), vD = bcast_f(mv, m + 3);
          acc += vA * h0r[(size_t)cA * HH + lane];
          acc += vB * h0r[(size_t)cB * HH + lane];
          acc += vC * h0r[(size_t)cC * HH + lane];
          acc += vD * h0r[(size_t)cD * HH + lane];
        }
      }
    }
    actS[(rr * 2 + 0) * 64 + lane] = acc;
  }
  // local h0 rows -> actS mat1
  for (int i = tid; i < 512; i += 256) {
    int r = i >> 6, k = i & 63;
    actS[(r * 2 + 1) * 64 + k] = h0r[(size_t)row0 * HH + i];
  }
  if (tid < 32) {
    int rloc = tid >> 2, comp = tid & 3;
    xgS[tid] = (comp < 2) ? xt[(size_t)(row0 + rloc) * 2 + comp]
                          : gaxt[(size_t)(row0 + rloc) * 2 + (comp - 2)];
  }
  __syncthreads();

  // acts -> registers (distinct-address b32 reads, conflict-free)
  float areg[4][2];
#pragma unroll
  for (int r = 0; r < 4; r++)
#pragma unroll
    for (int m = 0; m < 2; m++)
      areg[r][m] = actS[((rowgrp * 4 + r) * 2 + m) * 64 + lane];

  float2 b = biaspk0[ch * 64 + lane];
  float4 wA = xwA[ch * 64 + lane];
  float4 wB = xwB[ch * 64 + lane];
  float acc[4][2];
#pragma unroll
  for (int r = 0; r < 4; r++) {
    int rg = rowgrp * 4 + r;
    float x0 = xgS[rg * 4 + 0], x1 = xgS[rg * 4 + 1];
    float g0 = xgS[rg * 4 + 2], g1 = xgS[rg * 4 + 3];
    acc[r][0] = b.x + g0 * wA.x + g1 * wA.y + x0 * wA.z + x1 * wA.w;
    acc[r][1] = b.y + g0 * wB.x + g1 * wB.y + x0 * wB.z + x1 * wB.w;
  }
#pragma unroll 4
  for (int k = 0; k < 64; k++) {
    float2 w0 = Wpk0[((k * 2 + 0) * 2 + ch) * 64 + lane];
    float2 w1 = Wpk0[((k * 2 + 1) * 2 + ch) * 64 + lane];
#pragma unroll
    for (int r = 0; r < 4; r++) {
      float a0 = bcast_f(areg[r][0], k);
      float a1 = bcast_f(areg[r][1], k);
      acc[r][0] += a0 * w0.x + a1 * w1.x;
      acc[r][1] += a0 * w0.y + a1 * w1.y;
    }
  }
#pragma unroll
  for (int r = 0; r < 4; r++) {
    int rg = rowgrp * 4 + r;
    combS[rg * 256 + ch * 128 + lane] = acc[r][0];
    combS[rg * 256 + ch * 128 + 64 + lane] = acc[r][1];
  }
  __syncthreads();

  // gates: 512 outputs, 2/thread, coalesced; c-state in global
#pragma unroll
  for (int p = 0; p < 2; p++) {
    int o = tid + p * 256;
    int rr = o >> 6, hc = o & 63;
    float ig = combS[rr * 256 + hc];
    float fg = combS[rr * 256 + hc + 64];
    float og = combS[rr * 256 + hc + 128];
    float gg = combS[rr * 256 + hc + 192];
    size_t gi = (size_t)row0 * HH + o;
    float cprev = c0[gi];
    float si = 1.0f / (1.0f + __expf(-ig));
    float sf = 1.0f / (1.0f + __expf(-fg));
    float so = 1.0f / (1.0f + __expf(-og));
    float cn = sf * cprev + si * tanhf(gg);
    float hn = so * tanhf(cn);
    c0[gi] = cn;
    h0w[gi] = hn;
  }
}

// ---------------------------------------------------------------------------
// Cell 1: same structure, 4 act matrices {A@h0n, h0n, A@h1, h1} (dual gather).
// ---------------------------------------------------------------------------
__launch_bounds__(256, 2)
__global__ void k_cell1(const int* __restrict__ ell_col, const float* __restrict__ ell_val,
                        const int* __restrict__ ell_cnt,
                        const float* __restrict__ h0n,
                        const float* __restrict__ h1r, float* __restrict__ h1w,
                        float* __restrict__ c1,
                        const float2* __restrict__ Wpk1,
                        const float2* __restrict__ biaspk1) {
  const int row0 = blockIdx.x * 8;
  const int tid = threadIdx.x;
  const int wave = tid >> 6, lane = tid & 63;
  const int rowgrp = wave & 1, ch = wave >> 1;
  __shared__ float actS[8 * 4 * 64];   // [row][mat(4)][k]
  __shared__ float combS[8 * 256];

  int myc[2][3]; float myv[2][3]; int cnts[2];
#pragma unroll
  for (int half = 0; half < 2; half++) {
    int r = row0 + wave + half * 4;
    cnts[half] = ell_cnt[r];
#pragma unroll
    for (int chk = 0; chk < 3; chk++) {
      myc[half][chk] = ell_col[(size_t)r * CAP + chk * 64 + lane];
      myv[half][chk] = ell_val[(size_t)r * CAP + chk * 64 + lane];
    }
  }
#pragma unroll
  for (int half = 0; half < 2; half++) {
    int rr = wave + half * 4;
    int cnt = cnts[half];
    float a0 = 0.0f, a1 = 0.0f;
#pragma unroll
    for (int chk = 0; chk < 3; chk++) {
      int base = chk * 64;
      if (base < cnt) {
        int lim = cnt - base; if (lim > 64) lim = 64;
        int mc = myc[half][chk]; float mv = myv[half][chk];
        for (int m = 0; m < lim; m += 2) {
          int cA = bcast_i(mc, m), cB = bcast_i(mc, m + 1);
          float vA = bcast_f(mv, m), vB = bcast_f(mv, m + 1);
          a0 += vA * h0n[(size_t)cA * HH + lane];
          a1 += vA * h1r[(size_t)cA * HH + lane];
          a0 += vB * h0n[(size_t)cB * HH + lane];
          a1 += vB * h1r[(size_t)cB * HH + lane];
        }
      }
    }
    actS[(rr * 4 + 0) * 64 + lane] = a0;
    actS[(rr * 4 + 2) * 64 + lane] = a1;
  }
  for (int i = tid; i < 512; i += 256) {
    int r = i >> 6, k = i & 63;
    actS[(r * 4 + 1) * 64 + k] = h0n[(size_t)row0 * HH + i];
    actS[(r * 4 + 3) * 64 + k] = h1r[(size_t)row0 * HH + i];
  }
  __syncthreads();

  float areg[4][4];
#pragma unroll
  for (int r = 0; r < 4; r++)
#pragma unroll
    for (int m = 0; m < 4; m++)
      areg[r][m] = actS[((rowgrp * 4 + r) * 4 + m) * 64 + lane];

  float2 b = biaspk1[ch * 64 + lane];
  float acc[4][2];
#pragma unroll
  for (int r = 0; r < 4; r++) { acc[r][0] = b.x; acc[r][1] = b.y; }

#pragma unroll 4
  for (int k = 0; k < 64; k++) {
    float2 w0 = Wpk1[((k * 4 + 0) * 2 + ch) * 64 + lane];
    float2 w1 = Wpk1[((k * 4 + 1) * 2 + ch) * 64 + lane];
    float2 w2 = Wpk1[((k * 4 + 2) * 2 + ch) * 64 + lane];
    float2 w3 = Wpk1[((k * 4 + 3) * 2 + ch) * 64 + lane];
#pragma unroll
    for (int r = 0; r < 4; r++) {
      float a0 = bcast_f(areg[r][0], k);
      float a1 = bcast_f(areg[r][1], k);
      float a2 = bcast_f(areg[r][2], k);
      float a3 = bcast_f(areg[r][3], k);
      acc[r][0] += a0 * w0.x + a1 * w1.x + a2 * w2.x + a3 * w3.x;
      acc[r][1] += a0 * w0.y + a1 * w1.y + a2 * w2.y + a3 * w3.y;
    }
  }
#pragma unroll
  for (int r = 0; r < 4; r++) {
    int rg = rowgrp * 4 + r;
    combS[rg * 256 + ch * 128 + lane] = acc[r][0];
    combS[rg * 256 + ch * 128 + 64 + lane] = acc[r][1];
  }
  __syncthreads();

#pragma unroll
  for (int p = 0; p < 2; p++) {
    int o = tid + p * 256;
    int rr = o >> 6, hc = o & 63;
    float ig = combS[rr * 256 + hc];
    float fg = combS[rr * 256 + hc + 64];
    float og = combS[rr * 256 + hc + 128];
    float gg = combS[rr * 256 + hc + 192];
    size_t gi = (size_t)row0 * HH + o;
    float cprev = c1[gi];
    float si = 1.0f / (1.0f + __expf(-ig));
    float sf = 1.0f / (1.0f + __expf(-fg));
    float so = 1.0f / (1.0f + __expf(-og));
    float cn = sf * cprev + si * tanhf(gg);
    float hn = so * tanhf(cn);
    c1[gi] = cn;
    h1w[gi] = hn;
  }
}

// ---------------------------------------------------------------------------
// Output projection: out[r,p] = h1[r,:] @ outW[:,p] + outb[p].
// ---------------------------------------------------------------------------
__launch_bounds__(256)
__global__ void k_out(const float* __restrict__ h1, const float* __restrict__ outW,
                      const float* __restrict__ outb, float* __restrict__ out) {
  int idx = blockIdx.x * 256 + threadIdx.x;
  if (idx >= NN * PP) return;
  int r = idx / PP, p = idx - r * PP;
  float acc = outb[p];
  const float* hrow = h1 + (size_t)r * HH;
#pragma unroll 16
  for (int k = 0; k < HH; k++) acc += hrow[k] * outW[k * PP + p];
  out[idx] = acc;
}

extern "C" void kernel_launch(void* const* d_in, const int* in_sizes, int n_in,
                              void* d_out, int out_size, void* d_ws, size_t ws_size,
                              hipStream_t stream) {
  const float* x     = (const float*)d_in[0];
  const float* adj   = (const float*)d_in[1];
  const float* gcWi0 = (const float*)d_in[2];
  const float* gcbi0 = (const float*)d_in[3];
  const float* gcWh0 = (const float*)d_in[4];
  const float* gcbh0 = (const float*)d_in[5];
  const float* liWi0 = (const float*)d_in[6];
  const float* libi0 = (const float*)d_in[7];
  const float* liWh0 = (const float*)d_in[8];
  const float* libh0 = (const float*)d_in[9];
  const float* gcWi1 = (const float*)d_in[10];
  const float* gcbi1 = (const float*)d_in[11];
  const float* gcWh1 = (const float*)d_in[12];
  const float* gcbh1 = (const float*)d_in[13];
  const float* liWi1 = (const float*)d_in[14];
  const float* libi1 = (const float*)d_in[15];
  const float* liWh1 = (const float*)d_in[16];
  const float* libh1 = (const float*)d_in[17];
  const float* outW  = (const float*)d_in[18];
  const float* outb  = (const float*)d_in[19];

  char* ws = (char*)d_ws;
  size_t off = 0;
  auto carve = [&](size_t bytes) {
    void* p = ws + off;
    off += (bytes + 255) & ~(size_t)255;
    return p;
  };
  float*  dinv    = (float*)carve((size_t)NN * 4);
  int*    ell_col = (int*)carve((size_t)NN * CAP * 4);
  float*  ell_val = (float*)carve((size_t)NN * CAP * 4);
  int*    ell_cnt = (int*)carve((size_t)NN * 4);
  float*  state   = (float*)carve((size_t)6 * NH * 4);
  float*  gax     = (float*)carve((size_t)TT * NN * 2 * 4);
  float2* Wpk0    = (float2*)carve((size_t)64 * 256 * 8);
  float2* Wpk1    = (float2*)carve((size_t)64 * 512 * 8);
  float2* biaspk0 = (float2*)carve((size_t)128 * 8);
  float2* biaspk1 = (float2*)carve((size_t)128 * 8);
  float4* xwA     = (float4*)carve((size_t)128 * 16);
  float4* xwB     = (float4*)carve((size_t)128 * 16);

  float* h0buf[2] = {state, state + NH};
  float* h1buf[2] = {state + 2 * NH, state + 3 * NH};
  float* c0 = state + 4 * NH;
  float* c1 = state + 5 * NH;

  k_prep<<<512, 256, 0, stream>>>(gcbi0, gcbh0, libi0, libh0,
                                  gcbi1, gcbh1, libi1, libh1,
                                  gcWh0, liWh0, gcWi1, liWi1, gcWh1, liWh1,
                                  gcWi0, liWi0,
                                  state, Wpk0, Wpk1, biaspk0, biaspk1, xwA, xwB);
  k_build<<<NN, 256, 0, stream>>>(adj, dinv, ell_col, ell_val, ell_cnt);
  k_scale<<<(NN * CAP) / 256, 256, 0, stream>>>(dinv, ell_col, ell_val);
  k_gax<<<TT * 8, 256, 0, stream>>>(x, ell_col, ell_val, ell_cnt, gax);

  for (int t = 0; t < TT; t++) {
    int cur = t & 1;
    k_cell0<<<NN / 8, 256, 0, stream>>>(
        ell_col, ell_val, ell_cnt,
        h0buf[cur], h0buf[cur ^ 1], c0,
        x + (size_t)t * NN * 2, gax + (size_t)t * NN * 2,
        Wpk0, biaspk0, xwA, xwB);
    k_cell1<<<NN / 8, 256, 0, stream>>>(
        ell_col, ell_val, ell_cnt,
        h0buf[cur ^ 1],
        h1buf[cur], h1buf[cur ^ 1], c1,
        Wpk1, biaspk1);
  }

  // final h1 is h1buf[0] (t=47: cur=1, writes buf[0])
  k_out<<<(NN * PP + 255) / 256, 256, 0, stream>>>(state + 2 * NH, outW, outb,
                                                   (float*)d_out);
}

// Round 9
// 2918.718 us; speedup vs baseline: 2.7975x; 1.0905x over previous
//
#include <hip/hip_runtime.h>
#include <math.h>

// Problem constants
#define NN 4096
#define TT 48
#define HH 64
#define GG 256   // 4*H
#define PP 12
#define CAP 192  // ELL slots per row, 3 x 64 -> whole-wave chunk loads, no guard
#define NH (NN * HH)

// readlane broadcast: uniform lane index -> SGPR broadcast, off the LDS pipe
__device__ __forceinline__ float bcast_f(float v, int lane) {
  return __int_as_float(__builtin_amdgcn_readlane(__float_as_int(v), lane));
}
__device__ __forceinline__ int bcast_i(int v, int lane) {
  return __builtin_amdgcn_readlane(v, lane);
}

// ---------------------------------------------------------------------------
// h-state layout: paired buffers P[2], each [N][64][2] floats:
//   P[b][r][k][0] = h0[r][k], P[b][r][k][1] = h1[r][k].
// Step t (A = t&1): cell0 reads h0old = P[A^1][..][0], writes h0new = P[A][..][0].
//                   cell1 reads h0new+h1old from P[A] (ONE float2/gather-nnz),
//                         writes h1new = P[A^1][..][1].
// Final h1 (t=47, A=1) lands in P[0][..][1].
//
// Weight packs (col mapping: wave ch, lane j -> cols c0=ch*128+j, c1=c0+64):
//   Wq0[((k*2+ch)*2+w)*64+j] = float2{gcWh0,liWh0}[k][ch*128+w*64+j]
//   Wq1[((k*2+ch)*2+w)*64+j] = float4{gcWi1,liWi1,gcWh1,liWh1}[k][ch*128+w*64+j]
// ---------------------------------------------------------------------------
__launch_bounds__(256)
__global__ void k_prep(const float* gcbi0, const float* gcbh0,
                       const float* libi0, const float* libh0,
                       const float* gcbi1, const float* gcbh1,
                       const float* libi1, const float* libh1,
                       const float* gcWh0, const float* liWh0,
                       const float* gcWi1, const float* liWi1,
                       const float* gcWh1, const float* liWh1,
                       const float* gcWi0, const float* liWi0,
                       float* state, float2* Wq0, float4* Wq1,
                       float2* biaspk0, float2* biaspk1,
                       float4* xwA, float4* xwB) {
  int idx = blockIdx.x * 256 + threadIdx.x;
  int stride = gridDim.x * 256;
  for (int i = idx; i < 6 * NH; i += stride) state[i] = 0.0f;  // P0,P1,c0,c1
  for (int i = idx; i < 64 * 256; i += stride) {
    int j = i & 63, w = (i >> 6) & 1, ch = (i >> 7) & 1, k = i >> 8;
    int c = ch * 128 + w * 64 + j;
    Wq0[i] = make_float2(gcWh0[k * GG + c], liWh0[k * GG + c]);
    Wq1[i] = make_float4(gcWi1[k * GG + c], liWi1[k * GG + c],
                         gcWh1[k * GG + c], liWh1[k * GG + c]);
  }
  if (idx < 128) {
    int ch = idx >> 6, j = idx & 63;
    int c0 = ch * 128 + j, c1 = c0 + 64;
    biaspk0[idx] = make_float2(
        gcbi0[c0] + gcbh0[c0] + libi0[c0] + libh0[c0],
        gcbi0[c1] + gcbh0[c1] + libi0[c1] + libh0[c1]);
    biaspk1[idx] = make_float2(
        gcbi1[c0] + gcbh1[c0] + libi1[c0] + libh1[c0],
        gcbi1[c1] + gcbh1[c1] + libi1[c1] + libh1[c1]);
    xwA[idx] = make_float4(gcWi0[c0], gcWi0[GG + c0], liWi0[c0], liWi0[GG + c0]);
    xwB[idx] = make_float4(gcWi0[c1], gcWi0[GG + c1], liWi0[c1], liWi0[GG + c1]);
  }
}

// ---------------------------------------------------------------------------
// Single adj pass: raw ELL (incl. +I diag) + dinv. Zero-fills ALL CAP slots
// (re-poison semantics: padding must be (col=0, val=0)). cnt padded to x8
// (gather loops are unrolled 8-deep).
// ---------------------------------------------------------------------------
__launch_bounds__(256)
__global__ void k_build(const float* adj, float* dinv,
                        int* ell_col, float* ell_val, int* ell_cnt) {
  int r = blockIdx.x;
  __shared__ int cnt;
  __shared__ float red[256];
  if (threadIdx.x == 0) cnt = 0;
  __syncthreads();
  const float* row = adj + (size_t)r * NN;
  float s = 0.0f;
  for (int c = threadIdx.x; c < NN; c += 256) {
    float a = row[c];
    if (c == r) a += 1.0f;   // A = adj + I
    s += a;
    if (a != 0.0f) {
      int pos = atomicAdd(&cnt, 1);
      if (pos < CAP) {
        ell_col[(size_t)r * CAP + pos] = c;
        ell_val[(size_t)r * CAP + pos] = a;
      }
    }
  }
  red[threadIdx.x] = s;
  __syncthreads();
  for (int st = 128; st > 0; st >>= 1) {
    if (threadIdx.x < st) red[threadIdx.x] += red[threadIdx.x + st];
    __syncthreads();
  }
  int n = cnt < CAP ? cnt : CAP;
  for (int j = n + (int)threadIdx.x; j < CAP; j += 256) {
    ell_col[(size_t)r * CAP + j] = 0;
    ell_val[(size_t)r * CAP + j] = 0.0f;
  }
  if (threadIdx.x == 0) {
    int npad = (n + 7) & ~7;
    if (npad > CAP) npad = CAP;
    ell_cnt[r] = npad;
    dinv[r] = 1.0f / sqrtf(red[0]);  // rowsum + 1 >= 1
  }
}

__launch_bounds__(256)
__global__ void k_scale(const float* dinv, const int* ell_col, float* ell_val) {
  int idx = blockIdx.x * 256 + threadIdx.x;  // over NN*CAP
  int r = idx / CAP;
  if (r >= NN) return;
  float v = ell_val[idx];
  if (v != 0.0f) ell_val[idx] = v * dinv[r] * dinv[ell_col[idx]];
}

// ---------------------------------------------------------------------------
// Precompute gax[t][r][c] = (A @ x_t)[r][c]. Block = (t, 512-row segment).
// ---------------------------------------------------------------------------
__launch_bounds__(256)
__global__ void k_gax(const float* x, const int* ell_col, const float* ell_val,
                      const int* ell_cnt, float* gax) {
  int t = blockIdx.x >> 3;
  int seg = blockIdx.x & 7;
  __shared__ float xs[NN * 2];
  const float* xt = x + (size_t)t * NN * 2;
  for (int i = threadIdx.x; i < NN * 2; i += 256) xs[i] = xt[i];
  __syncthreads();
  int base = seg * 512 * 2;
  for (int oo = threadIdx.x; oo < 512 * 2; oo += 256) {
    int o = base + oo;
    int r = o >> 1, cmp = o & 1;
    int cnt = ell_cnt[r];
    const int* cp = ell_col + (size_t)r * CAP;
    const float* vp = ell_val + (size_t)r * CAP;
    float acc = 0.0f;
    for (int j = 0; j < cnt; j += 4) {
      acc += vp[j]     * xs[cp[j]     * 2 + cmp];
      acc += vp[j + 1] * xs[cp[j + 1] * 2 + cmp];
      acc += vp[j + 2] * xs[cp[j + 2] * 2 + cmp];
      acc += vp[j + 3] * xs[cp[j + 3] * 2 + cmp];
    }
    gax[(size_t)t * NN * 2 + o] = acc;
  }
}

// ---------------------------------------------------------------------------
// Cell 0. Block = 8 rows, 256 threads (4 waves; 2 blocks/CU -> 8 waves/CU).
// Gather: wave w does rows w, w+4; register ELL + readlane; 8 loads in
// flight per unrolled group. Dense: wave (rowgrp, ch) = 4 rows x 128 cols;
// weights in float2 {mat0,mat1} per col, 8-k register window (16 loads in
// flight) to break the R8 load->waitcnt->use serialization (VGPR 40 there).
// ---------------------------------------------------------------------------
__launch_bounds__(256, 2)
__global__ void k_cell0(const int* __restrict__ ell_col, const float* __restrict__ ell_val,
                        const int* __restrict__ ell_cnt,
                        const float2* __restrict__ Pr,   // read: h0old in .x
                        float* __restrict__ Pw,          // write: h0new -> [..]*2+0
                        float* __restrict__ c0,
                        const float* __restrict__ xt, const float* __restrict__ gaxt,
                        const float2* __restrict__ Wq0,
                        const float2* __restrict__ biaspk0,
                        const float4* __restrict__ xwA, const float4* __restrict__ xwB) {
  const int row0 = blockIdx.x * 8;
  const int tid = threadIdx.x;
  const int wave = tid >> 6, lane = tid & 63;
  const int rowgrp = wave & 1, ch = wave >> 1;
  __shared__ float actS[8 * 2 * 64];   // [row][mat(2)][k]
  __shared__ float combS[8 * 256];
  __shared__ float xgS[8 * 4];

  // ELL regs for gather rows (wave, wave+4)
  int myc[2][3]; float myv[2][3]; int cnts[2];
#pragma unroll
  for (int half = 0; half < 2; half++) {
    int r = row0 + wave + half * 4;
    cnts[half] = ell_cnt[r];
#pragma unroll
    for (int chk = 0; chk < 3; chk++) {
      myc[half][chk] = ell_col[(size_t)r * CAP + chk * 64 + lane];
      myv[half][chk] = ell_val[(size_t)r * CAP + chk * 64 + lane];
    }
  }
  // gather A@h0 rows (wave, wave+4); 8 independent loads per group
#pragma unroll
  for (int half = 0; half < 2; half++) {
    int rr = wave + half * 4;
    int cnt = cnts[half];
    float acc = 0.0f;
#pragma unroll
    for (int chk = 0; chk < 3; chk++) {
      int base = chk * 64;
      if (base < cnt) {
        int lim = cnt - base; if (lim > 64) lim = 64;  // multiple of 8
        int mc = myc[half][chk]; float mv = myv[half][chk];
        for (int m = 0; m < lim; m += 8) {
          float2 ld[8]; float vv[8];
#pragma unroll
          for (int i = 0; i < 8; i++) {
            int cc = bcast_i(mc, m + i);
            vv[i] = bcast_f(mv, m + i);
            ld[i] = Pr[(size_t)cc * 64 + lane];
          }
#pragma unroll
          for (int i = 0; i < 8; i++) acc += vv[i] * ld[i].x;
        }
      }
    }
    actS[(rr * 2 + 0) * 64 + lane] = acc;
  }
  // local h0 rows -> actS mat1
  for (int i = tid; i < 512; i += 256) {
    int r = i >> 6, k = i & 63;
    actS[(r * 2 + 1) * 64 + k] = Pr[(size_t)(row0 + r) * 64 + k].x;
  }
  if (tid < 32) {
    int rloc = tid >> 2, comp = tid & 3;
    xgS[tid] = (comp < 2) ? xt[(size_t)(row0 + rloc) * 2 + comp]
                          : gaxt[(size_t)(row0 + rloc) * 2 + (comp - 2)];
  }
  __syncthreads();

  // acts -> registers (distinct-address b32 reads, conflict-free)
  float areg[4][2];
#pragma unroll
  for (int r = 0; r < 4; r++)
#pragma unroll
    for (int m = 0; m < 2; m++)
      areg[r][m] = actS[((rowgrp * 4 + r) * 2 + m) * 64 + lane];

  float2 b = biaspk0[ch * 64 + lane];
  float4 wA = xwA[ch * 64 + lane];
  float4 wB = xwB[ch * 64 + lane];
  float acc[4][2];
#pragma unroll
  for (int r = 0; r < 4; r++) {
    int rg = rowgrp * 4 + r;
    float x0 = xgS[rg * 4 + 0], x1 = xgS[rg * 4 + 1];
    float g0 = xgS[rg * 4 + 2], g1 = xgS[rg * 4 + 3];
    acc[r][0] = b.x + g0 * wA.x + g1 * wA.y + x0 * wA.z + x1 * wA.w;
    acc[r][1] = b.y + g0 * wB.x + g1 * wB.y + x0 * wB.z + x1 * wB.w;
  }
  // dense: 8-k register window; base = Wq0 + ch*128 + lane, k-stride 256
  const float2* bq = Wq0 + ch * 128 + lane;
  for (int kw = 0; kw < 64; kw += 8) {
    float2 q0[8], q1[8];
#pragma unroll
    for (int u = 0; u < 8; u++) {
      q0[u] = bq[(kw + u) * 256];
      q1[u] = bq[(kw + u) * 256 + 64];
    }
#pragma unroll
    for (int u = 0; u < 8; u++) {
      int k = kw + u;
#pragma unroll
      for (int r = 0; r < 4; r++) {
        float a0 = bcast_f(areg[r][0], k);
        float a1 = bcast_f(areg[r][1], k);
        acc[r][0] += a0 * q0[u].x + a1 * q0[u].y;
        acc[r][1] += a0 * q1[u].x + a1 * q1[u].y;
      }
    }
  }
#pragma unroll
  for (int r = 0; r < 4; r++) {
    int rg = rowgrp * 4 + r;
    combS[rg * 256 + ch * 128 + lane] = acc[r][0];
    combS[rg * 256 + ch * 128 + 64 + lane] = acc[r][1];
  }
  __syncthreads();

  // gates: 512 outputs, 2/thread; h0new -> paired buffer slot 0
#pragma unroll
  for (int p = 0; p < 2; p++) {
    int o = tid + p * 256;
    int rr = o >> 6, hc = o & 63;
    float ig = combS[rr * 256 + hc];
    float fg = combS[rr * 256 + hc + 64];
    float og = combS[rr * 256 + hc + 128];
    float gg = combS[rr * 256 + hc + 192];
    size_t gi = (size_t)row0 * HH + o;
    float cprev = c0[gi];
    float si = 1.0f / (1.0f + __expf(-ig));
    float sf = 1.0f / (1.0f + __expf(-fg));
    float so = 1.0f / (1.0f + __expf(-og));
    float cn = sf * cprev + si * tanhf(gg);
    float hn = so * tanhf(cn);
    c0[gi] = cn;
    Pw[gi * 2 + 0] = hn;
  }
}

// ---------------------------------------------------------------------------
// Cell 1: dual gather reads ONE float2 {h0n, h1old} per nnz from the paired
// buffer; dense has 4 act mats, float4 weights, 8-k register window.
// ---------------------------------------------------------------------------
__launch_bounds__(256, 2)
__global__ void k_cell1(const int* __restrict__ ell_col, const float* __restrict__ ell_val,
                        const int* __restrict__ ell_cnt,
                        const float2* __restrict__ Pr,   // {h0n, h1old} pairs
                        float* __restrict__ Pw,          // h1new -> [..]*2+1
                        float* __restrict__ c1,
                        const float4* __restrict__ Wq1,
                        const float2* __restrict__ biaspk1) {
  const int row0 = blockIdx.x * 8;
  const int tid = threadIdx.x;
  const int wave = tid >> 6, lane = tid & 63;
  const int rowgrp = wave & 1, ch = wave >> 1;
  __shared__ float actS[8 * 4 * 64];   // [row][mat(4)][k]
  __shared__ float combS[8 * 256];

  int myc[2][3]; float myv[2][3]; int cnts[2];
#pragma unroll
  for (int half = 0; half < 2; half++) {
    int r = row0 + wave + half * 4;
    cnts[half] = ell_cnt[r];
#pragma unroll
    for (int chk = 0; chk < 3; chk++) {
      myc[half][chk] = ell_col[(size_t)r * CAP + chk * 64 + lane];
      myv[half][chk] = ell_val[(size_t)r * CAP + chk * 64 + lane];
    }
  }
#pragma unroll
  for (int half = 0; half < 2; half++) {
    int rr = wave + half * 4;
    int cnt = cnts[half];
    float a0 = 0.0f, a1 = 0.0f;
#pragma unroll
    for (int chk = 0; chk < 3; chk++) {
      int base = chk * 64;
      if (base < cnt) {
        int lim = cnt - base; if (lim > 64) lim = 64;  // multiple of 8
        int mc = myc[half][chk]; float mv = myv[half][chk];
        for (int m = 0; m < lim; m += 8) {
          float2 ld[8]; float vv[8];
#pragma unroll
          for (int i = 0; i < 8; i++) {
            int cc = bcast_i(mc, m + i);
            vv[i] = bcast_f(mv, m + i);
            ld[i] = Pr[(size_t)cc * 64 + lane];
          }
#pragma unroll
          for (int i = 0; i < 8; i++) {
            a0 += vv[i] * ld[i].x;
            a1 += vv[i] * ld[i].y;
          }
        }
      }
    }
    actS[(rr * 4 + 0) * 64 + lane] = a0;
    actS[(rr * 4 + 2) * 64 + lane] = a1;
  }
  for (int i = tid; i < 512; i += 256) {
    int r = i >> 6, k = i & 63;
    float2 hh = Pr[(size_t)(row0 + r) * 64 + k];
    actS[(r * 4 + 1) * 64 + k] = hh.x;
    actS[(r * 4 + 3) * 64 + k] = hh.y;
  }
  __syncthreads();

  float areg[4][4];
#pragma unroll
  for (int r = 0; r < 4; r++)
#pragma unroll
    for (int m = 0; m < 4; m++)
      areg[r][m] = actS[((rowgrp * 4 + r) * 4 + m) * 64 + lane];

  float2 b = biaspk1[ch * 64 + lane];
  float acc[4][2];
#pragma unroll
  for (int r = 0; r < 4; r++) { acc[r][0] = b.x; acc[r][1] = b.y; }

  // dense: 8-k window, 16 float4 loads in flight; base stride 256 float4/k
  const float4* bq = Wq1 + ch * 128 + lane;
  for (int kw = 0; kw < 64; kw += 8) {
    float4 q0[8], q1[8];
#pragma unroll
    for (int u = 0; u < 8; u++) {
      q0[u] = bq[(kw + u) * 256];
      q1[u] = bq[(kw + u) * 256 + 64];
    }
#pragma unroll
    for (int u = 0; u < 8; u++) {
      int k = kw + u;
#pragma unroll
      for (int r = 0; r < 4; r++) {
        float a0 = bcast_f(areg[r][0], k);
        float a1 = bcast_f(areg[r][1], k);
        float a2 = bcast_f(areg[r][2], k);
        float a3 = bcast_f(areg[r][3], k);
        acc[r][0] += a0 * q0[u].x + a1 * q0[u].y + a2 * q0[u].z + a3 * q0[u].w;
        acc[r][1] += a0 * q1[u].x + a1 * q1[u].y + a2 * q1[u].z + a3 * q1[u].w;
      }
    }
  }
#pragma unroll
  for (int r = 0; r < 4; r++) {
    int rg = rowgrp * 4 + r;
    combS[rg * 256 + ch * 128 + lane] = acc[r][0];
    combS[rg * 256 + ch * 128 + 64 + lane] = acc[r][1];
  }
  __syncthreads();

#pragma unroll
  for (int p = 0; p < 2; p++) {
    int o = tid + p * 256;
    int rr = o >> 6, hc = o & 63;
    float ig = combS[rr * 256 + hc];
    float fg = combS[rr * 256 + hc + 64];
    float og = combS[rr * 256 + hc + 128];
    float gg = combS[rr * 256 + hc + 192];
    size_t gi = (size_t)row0 * HH + o;
    float cprev = c1[gi];
    float si = 1.0f / (1.0f + __expf(-ig));
    float sf = 1.0f / (1.0f + __expf(-fg));
    float so = 1.0f / (1.0f + __expf(-og));
    float cn = sf * cprev + si * tanhf(gg);
    float hn = so * tanhf(cn);
    c1[gi] = cn;
    Pw[gi * 2 + 1] = hn;
  }
}

// ---------------------------------------------------------------------------
// Output projection: out[r,p] = h1[r,:] @ outW[:,p] + outb[p].
// h1 final = P0[..][1] (t=47: A=1, cell1 writes P[A^1]=P0).
// ---------------------------------------------------------------------------
__launch_bounds__(256)
__global__ void k_out(const float* __restrict__ P0, const float* __restrict__ outW,
                      const float* __restrict__ outb, float* __restrict__ out) {
  int idx = blockIdx.x * 256 + threadIdx.x;
  if (idx >= NN * PP) return;
  int r = idx / PP, p = idx - r * PP;
  float acc = outb[p];
  const float* hrow = P0 + (size_t)r * 128;
#pragma unroll 16
  for (int k = 0; k < HH; k++) acc += hrow[k * 2 + 1] * outW[k * PP + p];
  out[idx] = acc;
}

extern "C" void kernel_launch(void* const* d_in, const int* in_sizes, int n_in,
                              void* d_out, int out_size, void* d_ws, size_t ws_size,
                              hipStream_t stream) {
  const float* x     = (const float*)d_in[0];
  const float* adj   = (const float*)d_in[1];
  const float* gcWi0 = (const float*)d_in[2];
  const float* gcbi0 = (const float*)d_in[3];
  const float* gcWh0 = (const float*)d_in[4];
  const float* gcbh0 = (const float*)d_in[5];
  const float* liWi0 = (const float*)d_in[6];
  const float* libi0 = (const float*)d_in[7];
  const float* liWh0 = (const float*)d_in[8];
  const float* libh0 = (const float*)d_in[9];
  const float* gcWi1 = (const float*)d_in[10];
  const float* gcbi1 = (const float*)d_in[11];
  const float* gcWh1 = (const float*)d_in[12];
  const float* gcbh1 = (const float*)d_in[13];
  const float* liWi1 = (const float*)d_in[14];
  const float* libi1 = (const float*)d_in[15];
  const float* liWh1 = (const float*)d_in[16];
  const float* libh1 = (const float*)d_in[17];
  const float* outW  = (const float*)d_in[18];
  const float* outb  = (const float*)d_in[19];

  char* ws = (char*)d_ws;
  size_t off = 0;
  auto carve = [&](size_t bytes) {
    void* p = ws + off;
    off += (bytes + 255) & ~(size_t)255;
    return p;
  };
  float*  dinv    = (float*)carve((size_t)NN * 4);
  int*    ell_col = (int*)carve((size_t)NN * CAP * 4);
  float*  ell_val = (float*)carve((size_t)NN * CAP * 4);
  int*    ell_cnt = (int*)carve((size_t)NN * 4);
  float*  state   = (float*)carve((size_t)6 * NH * 4);  // P0,P1 (2NH each), c0, c1
  float*  gax     = (float*)carve((size_t)TT * NN * 2 * 4);
  float2* Wq0     = (float2*)carve((size_t)64 * 256 * 8);
  float4* Wq1     = (float4*)carve((size_t)64 * 256 * 16);
  float2* biaspk0 = (float2*)carve((size_t)128 * 8);
  float2* biaspk1 = (float2*)carve((size_t)128 * 8);
  float4* xwA     = (float4*)carve((size_t)128 * 16);
  float4* xwB     = (float4*)carve((size_t)128 * 16);

  float* P[2] = {state, state + 2 * NH};
  float* c0 = state + 4 * NH;
  float* c1 = state + 5 * NH;

  k_prep<<<512, 256, 0, stream>>>(gcbi0, gcbh0, libi0, libh0,
                                  gcbi1, gcbh1, libi1, libh1,
                                  gcWh0, liWh0, gcWi1, liWi1, gcWh1, liWh1,
                                  gcWi0, liWi0,
                                  state, Wq0, Wq1, biaspk0, biaspk1, xwA, xwB);
  k_build<<<NN, 256, 0, stream>>>(adj, dinv, ell_col, ell_val, ell_cnt);
  k_scale<<<(NN * CAP) / 256, 256, 0, stream>>>(dinv, ell_col, ell_val);
  k_gax<<<TT * 8, 256, 0, stream>>>(x, ell_col, ell_val, ell_cnt, gax);

  for (int t = 0; t < TT; t++) {
    int A = t & 1;
    // cell0: read h0old from P[A^1] (.x), write h0new into P[A] slot 0
    k_cell0<<<NN / 8, 256, 0, stream>>>(
        ell_col, ell_val, ell_cnt,
        (const float2*)P[A ^ 1], P[A], c0,
        x + (size_t)t * NN * 2, gax + (size_t)t * NN * 2,
        Wq0, biaspk0, xwA, xwB);
    // cell1: read {h0n,h1old} pairs from P[A], write h1new into P[A^1] slot 1
    k_cell1<<<NN / 8, 256, 0, stream>>>(
        ell_col, ell_val, ell_cnt,
        (const float2*)P[A], P[A ^ 1], c1,
        Wq1, biaspk1);
  }

  k_out<<<(NN * PP + 255) / 256, 256, 0, stream>>>(P[0], outW, outb, (float*)d_out);
}

// Round 10
// 2311.133 us; speedup vs baseline: 3.5330x; 1.2629x over previous
//
#include <hip/hip_runtime.h>
#include <math.h>

// Problem constants
#define NN 4096
#define TT 48
#define HH 64
#define GG 256   // 4*H
#define PP 12
#define CAP 192  // ELL slots per row, 3 x 64 -> whole-wave chunk loads, no guard
#define NH (NN * HH)

// readlane broadcast: uniform lane index -> SGPR broadcast, off the LDS pipe
__device__ __forceinline__ float bcast_f(float v, int lane) {
  return __int_as_float(__builtin_amdgcn_readlane(__float_as_int(v), lane));
}
__device__ __forceinline__ int bcast_i(int v, int lane) {
  return __builtin_amdgcn_readlane(v, lane);
}

// ---------------------------------------------------------------------------
// h-state layout: paired buffers P[2], each [N][64][2] floats:
//   P[b][r][k][0] = h0[r][k], P[b][r][k][1] = h1[r][k].
// Step t (A = t&1): cell0 reads h0old = P[A^1][..][0], writes h0new -> P[A][..][0].
//                   cell1 reads {h0new,h1old} from P[A] (ONE float2 per nnz),
//                         writes h1new -> P[A^1][..][1]. Final h1 in P[0][..][1].
//
// GATE-QUAD column mapping (the R9->R10 restructure): lane j owns cols
// {j, j+64, j+128, j+192} = the (i,f,o,g) gates of hidden unit j. One wave
// handles 2 rows x all 256 cols => a row's full gate quad lives in one lane's
// float4 acc. NO LDS, NO __syncthreads in the cell kernels.
// Weight packs (gate-quad vectors):
//   Wg0[(k*2+m)*64+j] = float4{W[k][j],W[k][j+64],W[k][j+128],W[k][j+192]},
//        m in {0:gcWh0, 1:liWh0}
//   Wg1[(k*4+m)*64+j] = same, m in {0:gcWi1, 1:liWi1, 2:gcWh1, 3:liWh1}
//   biasg0/biasg1[j]  = folded-bias gate quad
//   xq0[m*64+j], m in {0:gcWi0 k0, 1:gcWi0 k1, 2:liWi0 k0, 3:liWi0 k1}
// ---------------------------------------------------------------------------
__launch_bounds__(256)
__global__ void k_prep(const float* gcbi0, const float* gcbh0,
                       const float* libi0, const float* libh0,
                       const float* gcbi1, const float* gcbh1,
                       const float* libi1, const float* libh1,
                       const float* gcWh0, const float* liWh0,
                       const float* gcWi1, const float* liWi1,
                       const float* gcWh1, const float* liWh1,
                       const float* gcWi0, const float* liWi0,
                       float* state, float4* Wg0, float4* Wg1,
                       float4* biasg0, float4* biasg1, float4* xq0) {
  int idx = blockIdx.x * 256 + threadIdx.x;
  int stride = gridDim.x * 256;
  for (int i = idx; i < 6 * NH; i += stride) state[i] = 0.0f;  // P0,P1,c0,c1
  for (int i = idx; i < 64 * 2 * 64; i += stride) {
    int j = i & 63, m = (i >> 6) & 1, k = i >> 7;
    const float* W = m ? liWh0 : gcWh0;
    Wg0[i] = make_float4(W[k * GG + j], W[k * GG + j + 64],
                         W[k * GG + j + 128], W[k * GG + j + 192]);
  }
  for (int i = idx; i < 64 * 4 * 64; i += stride) {
    int j = i & 63, m = (i >> 6) & 3, k = i >> 8;
    const float* W = (m == 0) ? gcWi1 : (m == 1) ? liWi1 : (m == 2) ? gcWh1 : liWh1;
    Wg1[i] = make_float4(W[k * GG + j], W[k * GG + j + 64],
                         W[k * GG + j + 128], W[k * GG + j + 192]);
  }
  if (idx < 64) {
    int j = idx;
    biasg0[j] = make_float4(
        gcbi0[j] + gcbh0[j] + libi0[j] + libh0[j],
        gcbi0[j + 64] + gcbh0[j + 64] + libi0[j + 64] + libh0[j + 64],
        gcbi0[j + 128] + gcbh0[j + 128] + libi0[j + 128] + libh0[j + 128],
        gcbi0[j + 192] + gcbh0[j + 192] + libi0[j + 192] + libh0[j + 192]);
    biasg1[j] = make_float4(
        gcbi1[j] + gcbh1[j] + libi1[j] + libh1[j],
        gcbi1[j + 64] + gcbh1[j + 64] + libi1[j + 64] + libh1[j + 64],
        gcbi1[j + 128] + gcbh1[j + 128] + libi1[j + 128] + libh1[j + 128],
        gcbi1[j + 192] + gcbh1[j + 192] + libi1[j + 192] + libh1[j + 192]);
  } else if (idx < 320) {
    int i = idx - 64;           // i = m*64 + j
    int j = i & 63, m = i >> 6; // m: 0,1 -> gcWi0 row 0/1; 2,3 -> liWi0 row 0/1
    const float* W = (m < 2) ? gcWi0 : liWi0;
    int kk = m & 1;
    xq0[i] = make_float4(W[kk * GG + j], W[kk * GG + j + 64],
                         W[kk * GG + j + 128], W[kk * GG + j + 192]);
  }
}

// ---------------------------------------------------------------------------
// Single adj pass: raw ELL (incl. +I diag) + dinv. Zero-fills ALL CAP slots
// (re-poison semantics: padding must be (col=0, val=0)). cnt padded to x8
// (gather loops are unrolled 8-deep).
// ---------------------------------------------------------------------------
__launch_bounds__(256)
__global__ void k_build(const float* adj, float* dinv,
                        int* ell_col, float* ell_val, int* ell_cnt) {
  int r = blockIdx.x;
  __shared__ int cnt;
  __shared__ float red[256];
  if (threadIdx.x == 0) cnt = 0;
  __syncthreads();
  const float* row = adj + (size_t)r * NN;
  float s = 0.0f;
  for (int c = threadIdx.x; c < NN; c += 256) {
    float a = row[c];
    if (c == r) a += 1.0f;   // A = adj + I
    s += a;
    if (a != 0.0f) {
      int pos = atomicAdd(&cnt, 1);
      if (pos < CAP) {
        ell_col[(size_t)r * CAP + pos] = c;
        ell_val[(size_t)r * CAP + pos] = a;
      }
    }
  }
  red[threadIdx.x] = s;
  __syncthreads();
  for (int st = 128; st > 0; st >>= 1) {
    if (threadIdx.x < st) red[threadIdx.x] += red[threadIdx.x + st];
    __syncthreads();
  }
  int n = cnt < CAP ? cnt : CAP;
  for (int j = n + (int)threadIdx.x; j < CAP; j += 256) {
    ell_col[(size_t)r * CAP + j] = 0;
    ell_val[(size_t)r * CAP + j] = 0.0f;
  }
  if (threadIdx.x == 0) {
    int npad = (n + 7) & ~7;
    if (npad > CAP) npad = CAP;
    ell_cnt[r] = npad;
    dinv[r] = 1.0f / sqrtf(red[0]);  // rowsum + 1 >= 1
  }
}

__launch_bounds__(256)
__global__ void k_scale(const float* dinv, const int* ell_col, float* ell_val) {
  int idx = blockIdx.x * 256 + threadIdx.x;  // over NN*CAP
  int r = idx / CAP;
  if (r >= NN) return;
  float v = ell_val[idx];
  if (v != 0.0f) ell_val[idx] = v * dinv[r] * dinv[ell_col[idx]];
}

// ---------------------------------------------------------------------------
// Precompute gax[t][r][c] = (A @ x_t)[r][c]. Block = (t, 512-row segment).
// ---------------------------------------------------------------------------
__launch_bounds__(256)
__global__ void k_gax(const float* x, const int* ell_col, const float* ell_val,
                      const int* ell_cnt, float* gax) {
  int t = blockIdx.x >> 3;
  int seg = blockIdx.x & 7;
  __shared__ float xs[NN * 2];
  const float* xt = x + (size_t)t * NN * 2;
  for (int i = threadIdx.x; i < NN * 2; i += 256) xs[i] = xt[i];
  __syncthreads();
  int base = seg * 512 * 2;
  for (int oo = threadIdx.x; oo < 512 * 2; oo += 256) {
    int o = base + oo;
    int r = o >> 1, cmp = o & 1;
    int cnt = ell_cnt[r];
    const int* cp = ell_col + (size_t)r * CAP;
    const float* vp = ell_val + (size_t)r * CAP;
    float acc = 0.0f;
    for (int j = 0; j < cnt; j += 4) {
      acc += vp[j]     * xs[cp[j]     * 2 + cmp];
      acc += vp[j + 1] * xs[cp[j + 1] * 2 + cmp];
      acc += vp[j + 2] * xs[cp[j + 2] * 2 + cmp];
      acc += vp[j + 3] * xs[cp[j + 3] * 2 + cmp];
    }
    gax[(size_t)t * NN * 2 + o] = acc;
  }
}

// ---------------------------------------------------------------------------
// Cell 0 — barrier-free, LDS-free. Block = 8 rows x 256 threads; wave w owns
// rows {row0+2w, row0+2w+1} end-to-end: gather (register ELL + readlane,
// 8 loads in flight), dense (acts readlane'd from OWN registers; weights as
// gate-quad float4), gates (full quad in-lane), store.
// ---------------------------------------------------------------------------
__launch_bounds__(256)
__global__ void k_cell0(const int* __restrict__ ell_col, const float* __restrict__ ell_val,
                        const int* __restrict__ ell_cnt,
                        const float2* __restrict__ Pr,   // h0old in .x
                        float* __restrict__ Pw,          // h0new -> [..]*2+0
                        float* __restrict__ c0,
                        const float* __restrict__ xt, const float* __restrict__ gaxt,
                        const float4* __restrict__ Wg0,
                        const float4* __restrict__ biasg0,
                        const float4* __restrict__ xq0) {
  const int tid = threadIdx.x;
  const int wave = tid >> 6, lane = tid & 63;
  const int r0 = blockIdx.x * 8 + wave * 2;

  // ELL regs for my 2 rows
  int myc[2][3]; float myv[2][3]; int cnts[2];
#pragma unroll
  for (int rr = 0; rr < 2; rr++) {
    int r = r0 + rr;
    cnts[rr] = ell_cnt[r];
#pragma unroll
    for (int chk = 0; chk < 3; chk++) {
      myc[rr][chk] = ell_col[(size_t)r * CAP + chk * 64 + lane];
      myv[rr][chk] = ell_val[(size_t)r * CAP + chk * 64 + lane];
    }
  }
  // gather g[rr] = (A@h0old)[r0+rr][lane]; local h0 rows
  float gacc[2], hl[2];
#pragma unroll
  for (int rr = 0; rr < 2; rr++) {
    int cnt = cnts[rr];
    float acc = 0.0f;
#pragma unroll
    for (int chk = 0; chk < 3; chk++) {
      int base = chk * 64;
      if (base < cnt) {
        int lim = cnt - base; if (lim > 64) lim = 64;  // multiple of 8
        int mc = myc[rr][chk]; float mv = myv[rr][chk];
        for (int m = 0; m < lim; m += 8) {
          float2 ld[8]; float vv[8];
#pragma unroll
          for (int i = 0; i < 8; i++) {
            int cc = bcast_i(mc, m + i);
            vv[i] = bcast_f(mv, m + i);
            ld[i] = Pr[(size_t)cc * 64 + lane];
          }
#pragma unroll
          for (int i = 0; i < 8; i++) acc += vv[i] * ld[i].x;
        }
      }
    }
    gacc[rr] = acc;
    hl[rr] = Pr[(size_t)(r0 + rr) * 64 + lane].x;
  }

  // x-part init (x/gax scalars are wave-uniform loads -> scalarized)
  float4 acc[2];
  {
    float4 b = biasg0[lane];
    float4 qg0 = xq0[lane], qg1 = xq0[64 + lane];
    float4 ql0 = xq0[128 + lane], ql1 = xq0[192 + lane];
#pragma unroll
    for (int rr = 0; rr < 2; rr++) {
      float xx0 = xt[(size_t)(r0 + rr) * 2];
      float xx1 = xt[(size_t)(r0 + rr) * 2 + 1];
      float gg0 = gaxt[(size_t)(r0 + rr) * 2];
      float gg1 = gaxt[(size_t)(r0 + rr) * 2 + 1];
      acc[rr].x = b.x + gg0 * qg0.x + gg1 * qg1.x + xx0 * ql0.x + xx1 * ql1.x;
      acc[rr].y = b.y + gg0 * qg0.y + gg1 * qg1.y + xx0 * ql0.y + xx1 * ql1.y;
      acc[rr].z = b.z + gg0 * qg0.z + gg1 * qg1.z + xx0 * ql0.z + xx1 * ql1.z;
      acc[rr].w = b.w + gg0 * qg0.w + gg1 * qg1.w + xx0 * ql0.w + xx1 * ql1.w;
    }
  }

  // dense: per k, 2 gate-quad weight loads; acts from own registers
  const float4* bw = Wg0 + lane;
#pragma unroll 4
  for (int k = 0; k < 64; k++) {
    float4 w0 = bw[(k * 2 + 0) * 64];
    float4 w1 = bw[(k * 2 + 1) * 64];
#pragma unroll
    for (int rr = 0; rr < 2; rr++) {
      float a0 = bcast_f(gacc[rr], k);
      float a1 = bcast_f(hl[rr], k);
      acc[rr].x += a0 * w0.x + a1 * w1.x;
      acc[rr].y += a0 * w0.y + a1 * w1.y;
      acc[rr].z += a0 * w0.z + a1 * w1.z;
      acc[rr].w += a0 * w0.w + a1 * w1.w;
    }
  }

  // gates: lane holds the full quad for (row, hidden unit = lane)
#pragma unroll
  for (int rr = 0; rr < 2; rr++) {
    size_t gi = (size_t)(r0 + rr) * HH + lane;
    float cprev = c0[gi];
    float si = 1.0f / (1.0f + __expf(-acc[rr].x));
    float sf = 1.0f / (1.0f + __expf(-acc[rr].y));
    float so = 1.0f / (1.0f + __expf(-acc[rr].z));
    float cn = sf * cprev + si * tanhf(acc[rr].w);
    float hn = so * tanhf(cn);
    c0[gi] = cn;
    Pw[gi * 2 + 0] = hn;
  }
}

// ---------------------------------------------------------------------------
// Cell 1 — barrier-free, LDS-free; dual gather from paired {h0n,h1old} float2s.
// ---------------------------------------------------------------------------
__launch_bounds__(256)
__global__ void k_cell1(const int* __restrict__ ell_col, const float* __restrict__ ell_val,
                        const int* __restrict__ ell_cnt,
                        const float2* __restrict__ Pr,   // {h0n, h1old}
                        float* __restrict__ Pw,          // h1new -> [..]*2+1
                        float* __restrict__ c1,
                        const float4* __restrict__ Wg1,
                        const float4* __restrict__ biasg1) {
  const int tid = threadIdx.x;
  const int wave = tid >> 6, lane = tid & 63;
  const int r0 = blockIdx.x * 8 + wave * 2;

  int myc[2][3]; float myv[2][3]; int cnts[2];
#pragma unroll
  for (int rr = 0; rr < 2; rr++) {
    int r = r0 + rr;
    cnts[rr] = ell_cnt[r];
#pragma unroll
    for (int chk = 0; chk < 3; chk++) {
      myc[rr][chk] = ell_col[(size_t)r * CAP + chk * 64 + lane];
      myv[rr][chk] = ell_val[(size_t)r * CAP + chk * 64 + lane];
    }
  }
  float ga0[2], ga1[2], hl0[2], hl1[2];
#pragma unroll
  for (int rr = 0; rr < 2; rr++) {
    int cnt = cnts[rr];
    float a0 = 0.0f, a1 = 0.0f;
#pragma unroll
    for (int chk = 0; chk < 3; chk++) {
      int base = chk * 64;
      if (base < cnt) {
        int lim = cnt - base; if (lim > 64) lim = 64;  // multiple of 8
        int mc = myc[rr][chk]; float mv = myv[rr][chk];
        for (int m = 0; m < lim; m += 8) {
          float2 ld[8]; float vv[8];
#pragma unroll
          for (int i = 0; i < 8; i++) {
            int cc = bcast_i(mc, m + i);
            vv[i] = bcast_f(mv, m + i);
            ld[i] = Pr[(size_t)cc * 64 + lane];
          }
#pragma unroll
          for (int i = 0; i < 8; i++) {
            a0 += vv[i] * ld[i].x;
            a1 += vv[i] * ld[i].y;
          }
        }
      }
    }
    ga0[rr] = a0;
    ga1[rr] = a1;
    float2 hh = Pr[(size_t)(r0 + rr) * 64 + lane];
    hl0[rr] = hh.x;
    hl1[rr] = hh.y;
  }

  float4 acc[2];
  {
    float4 b = biasg1[lane];
    acc[0] = b; acc[1] = b;
  }
  const float4* bw = Wg1 + lane;
#pragma unroll 4
  for (int k = 0; k < 64; k++) {
    float4 w0 = bw[(k * 4 + 0) * 64];
    float4 w1 = bw[(k * 4 + 1) * 64];
    float4 w2 = bw[(k * 4 + 2) * 64];
    float4 w3 = bw[(k * 4 + 3) * 64];
#pragma unroll
    for (int rr = 0; rr < 2; rr++) {
      float a0 = bcast_f(ga0[rr], k);   // (A@h0n)   -> gcWi1
      float a1 = bcast_f(hl0[rr], k);   // h0n       -> liWi1
      float a2 = bcast_f(ga1[rr], k);   // (A@h1old) -> gcWh1
      float a3 = bcast_f(hl1[rr], k);   // h1old     -> liWh1
      acc[rr].x += a0 * w0.x + a1 * w1.x + a2 * w2.x + a3 * w3.x;
      acc[rr].y += a0 * w0.y + a1 * w1.y + a2 * w2.y + a3 * w3.y;
      acc[rr].z += a0 * w0.z + a1 * w1.z + a2 * w2.z + a3 * w3.z;
      acc[rr].w += a0 * w0.w + a1 * w1.w + a2 * w2.w + a3 * w3.w;
    }
  }

#pragma unroll
  for (int rr = 0; rr < 2; rr++) {
    size_t gi = (size_t)(r0 + rr) * HH + lane;
    float cprev = c1[gi];
    float si = 1.0f / (1.0f + __expf(-acc[rr].x));
    float sf = 1.0f / (1.0f + __expf(-acc[rr].y));
    float so = 1.0f / (1.0f + __expf(-acc[rr].z));
    float cn = sf * cprev + si * tanhf(acc[rr].w);
    float hn = so * tanhf(cn);
    c1[gi] = cn;
    Pw[gi * 2 + 1] = hn;
  }
}

// ---------------------------------------------------------------------------
// Output projection: out[r,p] = h1[r,:] @ outW[:,p] + outb[p].
// h1 final = P0[..][1] (t=47: A=1, cell1 writes P[A^1]=P0).
// ---------------------------------------------------------------------------
__launch_bounds__(256)
__global__ void k_out(const float* __restrict__ P0, const float* __restrict__ outW,
                      const float* __restrict__ outb, float* __restrict__ out) {
  int idx = blockIdx.x * 256 + threadIdx.x;
  if (idx >= NN * PP) return;
  int r = idx / PP, p = idx - r * PP;
  float acc = outb[p];
  const float* hrow = P0 + (size_t)r * 128;
#pragma unroll 16
  for (int k = 0; k < HH; k++) acc += hrow[k * 2 + 1] * outW[k * PP + p];
  out[idx] = acc;
}

extern "C" void kernel_launch(void* const* d_in, const int* in_sizes, int n_in,
                              void* d_out, int out_size, void* d_ws, size_t ws_size,
                              hipStream_t stream) {
  const float* x     = (const float*)d_in[0];
  const float* adj   = (const float*)d_in[1];
  const float* gcWi0 = (const float*)d_in[2];
  const float* gcbi0 = (const float*)d_in[3];
  const float* gcWh0 = (const float*)d_in[4];
  const float* gcbh0 = (const float*)d_in[5];
  const float* liWi0 = (const float*)d_in[6];
  const float* libi0 = (const float*)d_in[7];
  const float* liWh0 = (const float*)d_in[8];
  const float* libh0 = (const float*)d_in[9];
  const float* gcWi1 = (const float*)d_in[10];
  const float* gcbi1 = (const float*)d_in[11];
  const float* gcWh1 = (const float*)d_in[12];
  const float* gcbh1 = (const float*)d_in[13];
  const float* liWi1 = (const float*)d_in[14];
  const float* libi1 = (const float*)d_in[15];
  const float* liWh1 = (const float*)d_in[16];
  const float* libh1 = (const float*)d_in[17];
  const float* outW  = (const float*)d_in[18];
  const float* outb  = (const float*)d_in[19];

  char* ws = (char*)d_ws;
  size_t off = 0;
  auto carve = [&](size_t bytes) {
    void* p = ws + off;
    off += (bytes + 255) & ~(size_t)255;
    return p;
  };
  float*  dinv    = (float*)carve((size_t)NN * 4);
  int*    ell_col = (int*)carve((size_t)NN * CAP * 4);
  float*  ell_val = (float*)carve((size_t)NN * CAP * 4);
  int*    ell_cnt = (int*)carve((size_t)NN * 4);
  float*  state   = (float*)carve((size_t)6 * NH * 4);  // P0,P1 (2NH each), c0, c1
  float*  gax     = (float*)carve((size_t)TT * NN * 2 * 4);
  float4* Wg0     = (float4*)carve((size_t)64 * 2 * 64 * 16);
  float4* Wg1     = (float4*)carve((size_t)64 * 4 * 64 * 16);
  float4* biasg0  = (float4*)carve((size_t)64 * 16);
  float4* biasg1  = (float4*)carve((size_t)64 * 16);
  float4* xq0     = (float4*)carve((size_t)256 * 16);

  float* P[2] = {state, state + 2 * NH};
  float* c0 = state + 4 * NH;
  float* c1 = state + 5 * NH;

  k_prep<<<512, 256, 0, stream>>>(gcbi0, gcbh0, libi0, libh0,
                                  gcbi1, gcbh1, libi1, libh1,
                                  gcWh0, liWh0, gcWi1, liWi1, gcWh1, liWh1,
                                  gcWi0, liWi0,
                                  state, Wg0, Wg1, biasg0, biasg1, xq0);
  k_build<<<NN, 256, 0, stream>>>(adj, dinv, ell_col, ell_val, ell_cnt);
  k_scale<<<(NN * CAP) / 256, 256, 0, stream>>>(dinv, ell_col, ell_val);
  k_gax<<<TT * 8, 256, 0, stream>>>(x, ell_col, ell_val, ell_cnt, gax);

  for (int t = 0; t < TT; t++) {
    int A = t & 1;
    // cell0: read h0old from P[A^1] (.x), write h0new into P[A] slot 0
    k_cell0<<<NN / 8, 256, 0, stream>>>(
        ell_col, ell_val, ell_cnt,
        (const float2*)P[A ^ 1], P[A], c0,
        x + (size_t)t * NN * 2, gax + (size_t)t * NN * 2,
        Wg0, biasg0, xq0);
    // cell1: read {h0n,h1old} pairs from P[A], write h1new into P[A^1] slot 1
    k_cell1<<<NN / 8, 256, 0, stream>>>(
        ell_col, ell_val, ell_cnt,
        (const float2*)P[A], P[A ^ 1], c1,
        Wg1, biasg1);
  }

  k_out<<<(NN * PP + 255) / 256, 256, 0, stream>>>(P[0], outW, outb, (float*)d_out);
}

// Round 11
// 2080.112 us; speedup vs baseline: 3.9253x; 1.1111x over previous
//
#include <hip/hip_runtime.h>
#include <math.h>

// Problem constants
#define NN 4096
#define TT 48
#define HH 64
#define GG 256   // 4*H
#define PP 12
#define CAP 192  // ELL slots per row, 3 x 64 -> whole-wave chunk loads, no guard
#define NH (NN * HH)

// readlane broadcast: uniform lane index -> SGPR broadcast, off the LDS pipe
__device__ __forceinline__ float bcast_f(float v, int lane) {
  return __int_as_float(__builtin_amdgcn_readlane(__float_as_int(v), lane));
}
__device__ __forceinline__ int bcast_i(int v, int lane) {
  return __builtin_amdgcn_readlane(v, lane);
}

// ---------------------------------------------------------------------------
// h-state: paired buffers P[2], each [N][64][2]: {h0, h1} interleaved.
// Launch k (k=0..48) computes cell0(t=k) [k<48] and cell1(s=k-1) [k>0]:
//   READS only P[(k&1)^1]  (cell0: .x = h0(k-1); cell1: {h0(k-1), h1(k-2)})
//   WRITES only P[k&1]     (cell0 -> .x = h0(k);  cell1 -> .y = h1(k-1))
// Different 4B slots of the same float2 -> no intra-launch hazard, and the
// two roles are mutually independent => one fused launch, 96 -> 49 launches,
// 4 blocks/CU (16 waves/CU) with gather-latency waves co-scheduled against
// L2-bound dense waves. Final h1(47) lands in P[0].y.
//
// GATE-QUAD mapping: lane j owns cols {j, j+64, j+128, j+192} = (i,f,o,g) of
// hidden unit j. One wave = 2 rows x 256 cols; full quad in one lane's
// float4 acc. NO LDS, NO __syncthreads in the cell bodies.
//   Wg0[(k*2+m)*64+j] = float4 gate-quad, m in {gcWh0, liWh0}
//   Wg1[(k*4+m)*64+j] = float4 gate-quad, m in {gcWi1, liWi1, gcWh1, liWh1}
// ---------------------------------------------------------------------------
__launch_bounds__(256)
__global__ void k_prep(const float* gcbi0, const float* gcbh0,
                       const float* libi0, const float* libh0,
                       const float* gcbi1, const float* gcbh1,
                       const float* libi1, const float* libh1,
                       const float* gcWh0, const float* liWh0,
                       const float* gcWi1, const float* liWi1,
                       const float* gcWh1, const float* liWh1,
                       const float* gcWi0, const float* liWi0,
                       float* state, float4* Wg0, float4* Wg1,
                       float4* biasg0, float4* biasg1, float4* xq0) {
  int idx = blockIdx.x * 256 + threadIdx.x;
  int stride = gridDim.x * 256;
  for (int i = idx; i < 6 * NH; i += stride) state[i] = 0.0f;  // P0,P1,c0,c1
  for (int i = idx; i < 64 * 2 * 64; i += stride) {
    int j = i & 63, m = (i >> 6) & 1, k = i >> 7;
    const float* W = m ? liWh0 : gcWh0;
    Wg0[i] = make_float4(W[k * GG + j], W[k * GG + j + 64],
                         W[k * GG + j + 128], W[k * GG + j + 192]);
  }
  for (int i = idx; i < 64 * 4 * 64; i += stride) {
    int j = i & 63, m = (i >> 6) & 3, k = i >> 8;
    const float* W = (m == 0) ? gcWi1 : (m == 1) ? liWi1 : (m == 2) ? gcWh1 : liWh1;
    Wg1[i] = make_float4(W[k * GG + j], W[k * GG + j + 64],
                         W[k * GG + j + 128], W[k * GG + j + 192]);
  }
  if (idx < 64) {
    int j = idx;
    biasg0[j] = make_float4(
        gcbi0[j] + gcbh0[j] + libi0[j] + libh0[j],
        gcbi0[j + 64] + gcbh0[j + 64] + libi0[j + 64] + libh0[j + 64],
        gcbi0[j + 128] + gcbh0[j + 128] + libi0[j + 128] + libh0[j + 128],
        gcbi0[j + 192] + gcbh0[j + 192] + libi0[j + 192] + libh0[j + 192]);
    biasg1[j] = make_float4(
        gcbi1[j] + gcbh1[j] + libi1[j] + libh1[j],
        gcbi1[j + 64] + gcbh1[j + 64] + libi1[j + 64] + libh1[j + 64],
        gcbi1[j + 128] + gcbh1[j + 128] + libi1[j + 128] + libh1[j + 128],
        gcbi1[j + 192] + gcbh1[j + 192] + libi1[j + 192] + libh1[j + 192]);
  } else if (idx < 320) {
    int i = idx - 64;           // i = m*64 + j
    int j = i & 63, m = i >> 6; // m: 0,1 -> gcWi0 row 0/1; 2,3 -> liWi0 row 0/1
    const float* W = (m < 2) ? gcWi0 : liWi0;
    int kk = m & 1;
    xq0[i] = make_float4(W[kk * GG + j], W[kk * GG + j + 64],
                         W[kk * GG + j + 128], W[kk * GG + j + 192]);
  }
}

// ---------------------------------------------------------------------------
// Single adj pass: raw ELL (incl. +I diag) + dinv. Zero-fills ALL CAP slots
// (re-poison semantics: padding must be (col=0, val=0)). cnt padded to x8.
// ---------------------------------------------------------------------------
__launch_bounds__(256)
__global__ void k_build(const float* adj, float* dinv,
                        int* ell_col, float* ell_val, int* ell_cnt) {
  int r = blockIdx.x;
  __shared__ int cnt;
  __shared__ float red[256];
  if (threadIdx.x == 0) cnt = 0;
  __syncthreads();
  const float* row = adj + (size_t)r * NN;
  float s = 0.0f;
  for (int c = threadIdx.x; c < NN; c += 256) {
    float a = row[c];
    if (c == r) a += 1.0f;   // A = adj + I
    s += a;
    if (a != 0.0f) {
      int pos = atomicAdd(&cnt, 1);
      if (pos < CAP) {
        ell_col[(size_t)r * CAP + pos] = c;
        ell_val[(size_t)r * CAP + pos] = a;
      }
    }
  }
  red[threadIdx.x] = s;
  __syncthreads();
  for (int st = 128; st > 0; st >>= 1) {
    if (threadIdx.x < st) red[threadIdx.x] += red[threadIdx.x + st];
    __syncthreads();
  }
  int n = cnt < CAP ? cnt : CAP;
  for (int j = n + (int)threadIdx.x; j < CAP; j += 256) {
    ell_col[(size_t)r * CAP + j] = 0;
    ell_val[(size_t)r * CAP + j] = 0.0f;
  }
  if (threadIdx.x == 0) {
    int npad = (n + 7) & ~7;
    if (npad > CAP) npad = CAP;
    ell_cnt[r] = npad;
    dinv[r] = 1.0f / sqrtf(red[0]);  // rowsum + 1 >= 1
  }
}

__launch_bounds__(256)
__global__ void k_scale(const float* dinv, const int* ell_col, float* ell_val) {
  int idx = blockIdx.x * 256 + threadIdx.x;  // over NN*CAP
  int r = idx / CAP;
  if (r >= NN) return;
  float v = ell_val[idx];
  if (v != 0.0f) ell_val[idx] = v * dinv[r] * dinv[ell_col[idx]];
}

// ---------------------------------------------------------------------------
// Precompute gax[t][r][c] = (A @ x_t)[r][c]. Block = (t, 512-row segment).
// ---------------------------------------------------------------------------
__launch_bounds__(256)
__global__ void k_gax(const float* x, const int* ell_col, const float* ell_val,
                      const int* ell_cnt, float* gax) {
  int t = blockIdx.x >> 3;
  int seg = blockIdx.x & 7;
  __shared__ float xs[NN * 2];
  const float* xt = x + (size_t)t * NN * 2;
  for (int i = threadIdx.x; i < NN * 2; i += 256) xs[i] = xt[i];
  __syncthreads();
  int base = seg * 512 * 2;
  for (int oo = threadIdx.x; oo < 512 * 2; oo += 256) {
    int o = base + oo;
    int r = o >> 1, cmp = o & 1;
    int cnt = ell_cnt[r];
    const int* cp = ell_col + (size_t)r * CAP;
    const float* vp = ell_val + (size_t)r * CAP;
    float acc = 0.0f;
    for (int j = 0; j < cnt; j += 4) {
      acc += vp[j]     * xs[cp[j]     * 2 + cmp];
      acc += vp[j + 1] * xs[cp[j + 1] * 2 + cmp];
      acc += vp[j + 2] * xs[cp[j + 2] * 2 + cmp];
      acc += vp[j + 3] * xs[cp[j + 3] * 2 + cmp];
    }
    gax[(size_t)t * NN * 2 + o] = acc;
  }
}

// ---------------------------------------------------------------------------
// Cell 0 body (one block of 8 rows): barrier-free, LDS-free (R10-proven).
// ---------------------------------------------------------------------------
__device__ __forceinline__ void cell0_body(
    int blk,
    const int* __restrict__ ell_col, const float* __restrict__ ell_val,
    const int* __restrict__ ell_cnt,
    const float2* __restrict__ Pr, float* __restrict__ Pw,
    float* __restrict__ c0,
    const float* __restrict__ xt, const float* __restrict__ gaxt,
    const float4* __restrict__ Wg0, const float4* __restrict__ biasg0,
    const float4* __restrict__ xq0) {
  const int tid = threadIdx.x;
  const int wave = tid >> 6, lane = tid & 63;
  const int r0 = blk * 8 + wave * 2;

  int myc[2][3]; float myv[2][3]; int cnts[2];
#pragma unroll
  for (int rr = 0; rr < 2; rr++) {
    int r = r0 + rr;
    cnts[rr] = ell_cnt[r];
#pragma unroll
    for (int chk = 0; chk < 3; chk++) {
      myc[rr][chk] = ell_col[(size_t)r * CAP + chk * 64 + lane];
      myv[rr][chk] = ell_val[(size_t)r * CAP + chk * 64 + lane];
    }
  }
  float gacc[2], hl[2];
#pragma unroll
  for (int rr = 0; rr < 2; rr++) {
    int cnt = cnts[rr];
    float acc = 0.0f;
#pragma unroll
    for (int chk = 0; chk < 3; chk++) {
      int base = chk * 64;
      if (base < cnt) {
        int lim = cnt - base; if (lim > 64) lim = 64;  // multiple of 8
        int mc = myc[rr][chk]; float mv = myv[rr][chk];
        for (int m = 0; m < lim; m += 8) {
          float2 ld[8]; float vv[8];
#pragma unroll
          for (int i = 0; i < 8; i++) {
            int cc = bcast_i(mc, m + i);
            vv[i] = bcast_f(mv, m + i);
            ld[i] = Pr[(size_t)cc * 64 + lane];
          }
#pragma unroll
          for (int i = 0; i < 8; i++) acc += vv[i] * ld[i].x;
        }
      }
    }
    gacc[rr] = acc;
    hl[rr] = Pr[(size_t)(r0 + rr) * 64 + lane].x;
  }

  float4 acc[2];
  {
    float4 b = biasg0[lane];
    float4 qg0 = xq0[lane], qg1 = xq0[64 + lane];
    float4 ql0 = xq0[128 + lane], ql1 = xq0[192 + lane];
#pragma unroll
    for (int rr = 0; rr < 2; rr++) {
      float xx0 = xt[(size_t)(r0 + rr) * 2];
      float xx1 = xt[(size_t)(r0 + rr) * 2 + 1];
      float gg0 = gaxt[(size_t)(r0 + rr) * 2];
      float gg1 = gaxt[(size_t)(r0 + rr) * 2 + 1];
      acc[rr].x = b.x + gg0 * qg0.x + gg1 * qg1.x + xx0 * ql0.x + xx1 * ql1.x;
      acc[rr].y = b.y + gg0 * qg0.y + gg1 * qg1.y + xx0 * ql0.y + xx1 * ql1.y;
      acc[rr].z = b.z + gg0 * qg0.z + gg1 * qg1.z + xx0 * ql0.z + xx1 * ql1.z;
      acc[rr].w = b.w + gg0 * qg0.w + gg1 * qg1.w + xx0 * ql0.w + xx1 * ql1.w;
    }
  }

  const float4* bw = Wg0 + lane;
#pragma unroll 4
  for (int k = 0; k < 64; k++) {
    float4 w0 = bw[(k * 2 + 0) * 64];
    float4 w1 = bw[(k * 2 + 1) * 64];
#pragma unroll
    for (int rr = 0; rr < 2; rr++) {
      float a0 = bcast_f(gacc[rr], k);
      float a1 = bcast_f(hl[rr], k);
      acc[rr].x += a0 * w0.x + a1 * w1.x;
      acc[rr].y += a0 * w0.y + a1 * w1.y;
      acc[rr].z += a0 * w0.z + a1 * w1.z;
      acc[rr].w += a0 * w0.w + a1 * w1.w;
    }
  }

#pragma unroll
  for (int rr = 0; rr < 2; rr++) {
    size_t gi = (size_t)(r0 + rr) * HH + lane;
    float cprev = c0[gi];
    float si = 1.0f / (1.0f + __expf(-acc[rr].x));
    float sf = 1.0f / (1.0f + __expf(-acc[rr].y));
    float so = 1.0f / (1.0f + __expf(-acc[rr].z));
    float cn = sf * cprev + si * tanhf(acc[rr].w);
    float hn = so * tanhf(cn);
    c0[gi] = cn;
    Pw[gi * 2 + 0] = hn;
  }
}

// ---------------------------------------------------------------------------
// Cell 1 body (one block of 8 rows): dual gather from paired {h0n,h1old}.
// ---------------------------------------------------------------------------
__device__ __forceinline__ void cell1_body(
    int blk,
    const int* __restrict__ ell_col, const float* __restrict__ ell_val,
    const int* __restrict__ ell_cnt,
    const float2* __restrict__ Pr, float* __restrict__ Pw,
    float* __restrict__ c1,
    const float4* __restrict__ Wg1, const float4* __restrict__ biasg1) {
  const int tid = threadIdx.x;
  const int wave = tid >> 6, lane = tid & 63;
  const int r0 = blk * 8 + wave * 2;

  int myc[2][3]; float myv[2][3]; int cnts[2];
#pragma unroll
  for (int rr = 0; rr < 2; rr++) {
    int r = r0 + rr;
    cnts[rr] = ell_cnt[r];
#pragma unroll
    for (int chk = 0; chk < 3; chk++) {
      myc[rr][chk] = ell_col[(size_t)r * CAP + chk * 64 + lane];
      myv[rr][chk] = ell_val[(size_t)r * CAP + chk * 64 + lane];
    }
  }
  float ga0[2], ga1[2], hl0[2], hl1[2];
#pragma unroll
  for (int rr = 0; rr < 2; rr++) {
    int cnt = cnts[rr];
    float a0 = 0.0f, a1 = 0.0f;
#pragma unroll
    for (int chk = 0; chk < 3; chk++) {
      int base = chk * 64;
      if (base < cnt) {
        int lim = cnt - base; if (lim > 64) lim = 64;  // multiple of 8
        int mc = myc[rr][chk]; float mv = myv[rr][chk];
        for (int m = 0; m < lim; m += 8) {
          float2 ld[8]; float vv[8];
#pragma unroll
          for (int i = 0; i < 8; i++) {
            int cc = bcast_i(mc, m + i);
            vv[i] = bcast_f(mv, m + i);
            ld[i] = Pr[(size_t)cc * 64 + lane];
          }
#pragma unroll
          for (int i = 0; i < 8; i++) {
            a0 += vv[i] * ld[i].x;
            a1 += vv[i] * ld[i].y;
          }
        }
      }
    }
    ga0[rr] = a0;
    ga1[rr] = a1;
    float2 hh = Pr[(size_t)(r0 + rr) * 64 + lane];
    hl0[rr] = hh.x;
    hl1[rr] = hh.y;
  }

  float4 acc[2];
  {
    float4 b = biasg1[lane];
    acc[0] = b; acc[1] = b;
  }
  const float4* bw = Wg1 + lane;
#pragma unroll 4
  for (int k = 0; k < 64; k++) {
    float4 w0 = bw[(k * 4 + 0) * 64];
    float4 w1 = bw[(k * 4 + 1) * 64];
    float4 w2 = bw[(k * 4 + 2) * 64];
    float4 w3 = bw[(k * 4 + 3) * 64];
#pragma unroll
    for (int rr = 0; rr < 2; rr++) {
      float a0 = bcast_f(ga0[rr], k);   // (A@h0n)   -> gcWi1
      float a1 = bcast_f(hl0[rr], k);   // h0n       -> liWi1
      float a2 = bcast_f(ga1[rr], k);   // (A@h1old) -> gcWh1
      float a3 = bcast_f(hl1[rr], k);   // h1old     -> liWh1
      acc[rr].x += a0 * w0.x + a1 * w1.x + a2 * w2.x + a3 * w3.x;
      acc[rr].y += a0 * w0.y + a1 * w1.y + a2 * w2.y + a3 * w3.y;
      acc[rr].z += a0 * w0.z + a1 * w1.z + a2 * w2.z + a3 * w3.z;
      acc[rr].w += a0 * w0.w + a1 * w1.w + a2 * w2.w + a3 * w3.w;
    }
  }

#pragma unroll
  for (int rr = 0; rr < 2; rr++) {
    size_t gi = (size_t)(r0 + rr) * HH + lane;
    float cprev = c1[gi];
    float si = 1.0f / (1.0f + __expf(-acc[rr].x));
    float sf = 1.0f / (1.0f + __expf(-acc[rr].y));
    float so = 1.0f / (1.0f + __expf(-acc[rr].z));
    float cn = sf * cprev + si * tanhf(acc[rr].w);
    float hn = so * tanhf(cn);
    c1[gi] = cn;
    Pw[gi * 2 + 1] = hn;
  }
}

// ---------------------------------------------------------------------------
// Fused step kernel: blocks [0, c0blocks) run cell0(t); the rest run
// cell1(t-1). The two roles are independent (see header comment): the launch
// reads only Pr and writes only Pw (disjoint float2 slots).
// ---------------------------------------------------------------------------
__launch_bounds__(256)
__global__ void k_cells(int c0blocks,
                        const int* __restrict__ ell_col,
                        const float* __restrict__ ell_val,
                        const int* __restrict__ ell_cnt,
                        const float2* __restrict__ Pr, float* __restrict__ Pw,
                        float* __restrict__ c0, float* __restrict__ c1,
                        const float* __restrict__ xt, const float* __restrict__ gaxt,
                        const float4* __restrict__ Wg0,
                        const float4* __restrict__ biasg0,
                        const float4* __restrict__ xq0,
                        const float4* __restrict__ Wg1,
                        const float4* __restrict__ biasg1) {
  int b = blockIdx.x;
  if (b < c0blocks) {
    cell0_body(b, ell_col, ell_val, ell_cnt, Pr, Pw, c0, xt, gaxt,
               Wg0, biasg0, xq0);
  } else {
    cell1_body(b - c0blocks, ell_col, ell_val, ell_cnt, Pr, Pw, c1,
               Wg1, biasg1);
  }
}

// ---------------------------------------------------------------------------
// Output projection: out[r,p] = h1[r,:] @ outW[:,p] + outb[p].
// h1 final = P0[..][1] (launch 48 writes P[0].y).
// ---------------------------------------------------------------------------
__launch_bounds__(256)
__global__ void k_out(const float* __restrict__ P0, const float* __restrict__ outW,
                      const float* __restrict__ outb, float* __restrict__ out) {
  int idx = blockIdx.x * 256 + threadIdx.x;
  if (idx >= NN * PP) return;
  int r = idx / PP, p = idx - r * PP;
  float acc = outb[p];
  const float* hrow = P0 + (size_t)r * 128;
#pragma unroll 16
  for (int k = 0; k < HH; k++) acc += hrow[k * 2 + 1] * outW[k * PP + p];
  out[idx] = acc;
}

extern "C" void kernel_launch(void* const* d_in, const int* in_sizes, int n_in,
                              void* d_out, int out_size, void* d_ws, size_t ws_size,
                              hipStream_t stream) {
  const float* x     = (const float*)d_in[0];
  const float* adj   = (const float*)d_in[1];
  const float* gcWi0 = (const float*)d_in[2];
  const float* gcbi0 = (const float*)d_in[3];
  const float* gcWh0 = (const float*)d_in[4];
  const float* gcbh0 = (const float*)d_in[5];
  const float* liWi0 = (const float*)d_in[6];
  const float* libi0 = (const float*)d_in[7];
  const float* liWh0 = (const float*)d_in[8];
  const float* libh0 = (const float*)d_in[9];
  const float* gcWi1 = (const float*)d_in[10];
  const float* gcbi1 = (const float*)d_in[11];
  const float* gcWh1 = (const float*)d_in[12];
  const float* gcbh1 = (const float*)d_in[13];
  const float* liWi1 = (const float*)d_in[14];
  const float* libi1 = (const float*)d_in[15];
  const float* liWh1 = (const float*)d_in[16];
  const float* libh1 = (const float*)d_in[17];
  const float* outW  = (const float*)d_in[18];
  const float* outb  = (const float*)d_in[19];

  char* ws = (char*)d_ws;
  size_t off = 0;
  auto carve = [&](size_t bytes) {
    void* p = ws + off;
    off += (bytes + 255) & ~(size_t)255;
    return p;
  };
  float*  dinv    = (float*)carve((size_t)NN * 4);
  int*    ell_col = (int*)carve((size_t)NN * CAP * 4);
  float*  ell_val = (float*)carve((size_t)NN * CAP * 4);
  int*    ell_cnt = (int*)carve((size_t)NN * 4);
  float*  state   = (float*)carve((size_t)6 * NH * 4);  // P0,P1 (2NH each), c0, c1
  float*  gax     = (float*)carve((size_t)TT * NN * 2 * 4);
  float4* Wg0     = (float4*)carve((size_t)64 * 2 * 64 * 16);
  float4* Wg1     = (float4*)carve((size_t)64 * 4 * 64 * 16);
  float4* biasg0  = (float4*)carve((size_t)64 * 16);
  float4* biasg1  = (float4*)carve((size_t)64 * 16);
  float4* xq0     = (float4*)carve((size_t)256 * 16);

  float* P[2] = {state, state + 2 * NH};
  float* c0 = state + 4 * NH;
  float* c1 = state + 5 * NH;

  k_prep<<<512, 256, 0, stream>>>(gcbi0, gcbh0, libi0, libh0,
                                  gcbi1, gcbh1, libi1, libh1,
                                  gcWh0, liWh0, gcWi1, liWi1, gcWh1, liWh1,
                                  gcWi0, liWi0,
                                  state, Wg0, Wg1, biasg0, biasg1, xq0);
  k_build<<<NN, 256, 0, stream>>>(adj, dinv, ell_col, ell_val, ell_cnt);
  k_scale<<<(NN * CAP) / 256, 256, 0, stream>>>(dinv, ell_col, ell_val);
  k_gax<<<TT * 8, 256, 0, stream>>>(x, ell_col, ell_val, ell_cnt, gax);

  // Software-pipelined step loop: launch k runs {cell0(k) || cell1(k-1)}.
  // Launch k reads P[(k&1)^1], writes P[k&1].
  for (int k = 0; k <= TT; k++) {
    int A = k & 1;
    int c0blocks = (k < TT) ? NN / 8 : 0;          // cell0 active for k<48
    int c1blocks = (k > 0) ? NN / 8 : 0;           // cell1 active for k>0
    int grid = c0blocks + c1blocks;
    int tx = (k < TT) ? k : (TT - 1);              // xt/gaxt unused when k==TT
    k_cells<<<grid, 256, 0, stream>>>(
        c0blocks, ell_col, ell_val, ell_cnt,
        (const float2*)P[A ^ 1], P[A], c0, c1,
        x + (size_t)tx * NN * 2, gax + (size_t)tx * NN * 2,
        Wg0, biasg0, xq0, Wg1, biasg1);
  }

  // Launch 48 (A=0) wrote h1(47) into P[0].y
  k_out<<<(NN * PP + 255) / 256, 256, 0, stream>>>(P[0], outW, outb, (float*)d_out);
}